// Round 1
// baseline (1479.700 us; speedup 1.0000x reference)
//
#include <hip/hip_runtime.h>
#include <cstddef>

#define D_MODEL   512
#define FF        2048
#define D_STATE   128
#define D_INNER   1024
#define HEADDIM   64
#define NHEADS    16
#define CONV_DIM  1280
#define D_IN_PROJ 2320
#define B_SZ      2
#define SEQ       2048
#define NTOK      (B_SZ*SEQ)   // 4096

__device__ __forceinline__ float sigmoid_f(float x){ return 1.0f/(1.0f+expf(-x)); }
__device__ __forceinline__ float gelu_f(float x){ return 0.5f*x*(1.0f+erff(x*0.70710678118654752f)); }

// ---------------- fp32 GEMM: C = A(MxK) @ W(KxN) [+bias] [+gelu] --------------
// BM=128, BN=64, BK=16, 256 threads, 8x4 per thread.
template<int EPI>  // 0: none, 1: +bias, 2: gelu(.+bias)
__global__ __launch_bounds__(256)
void gemm_f32(const float* __restrict__ A, const float* __restrict__ W,
              const float* __restrict__ bias, float* __restrict__ Cout,
              int M, int N, int K)
{
  constexpr int BM=128, BN=64, BK=16;
  __shared__ float As[BK][BM+4];   // ld=132: float4-aligned reads, ~2-way write conflicts
  __shared__ float Ws[BK][BN+4];   // ld=68
  const int bm = blockIdx.y*BM, bn = blockIdx.x*BN;
  const int tid = threadIdx.x;
  const int tx = tid & 15, ty = tid >> 4;
  const int arow = tid >> 1;          // 0..127
  const int akc  = (tid & 1) * 8;     // 0 or 8
  const int wk   = tid >> 4;          // 0..15
  const int wn   = (tid & 15) * 4;    // 0..60

  float acc[8][4];
  #pragma unroll
  for (int i=0;i<8;i++)
    #pragma unroll
    for (int j=0;j<4;j++) acc[i][j]=0.f;

  const float* Arow = A + (size_t)(bm+arow)*K + akc;

  for (int k0=0; k0<K; k0+=BK) {
    float4 av0 = *(const float4*)(Arow + k0);
    float4 av1 = *(const float4*)(Arow + k0 + 4);
    As[akc+0][arow]=av0.x; As[akc+1][arow]=av0.y; As[akc+2][arow]=av0.z; As[akc+3][arow]=av0.w;
    As[akc+4][arow]=av1.x; As[akc+5][arow]=av1.y; As[akc+6][arow]=av1.z; As[akc+7][arow]=av1.w;
    const int wcol = bn + wn;
    if (wcol + 3 < N) {
      float4 wv = *(const float4*)(W + (size_t)(k0+wk)*N + wcol);
      Ws[wk][wn+0]=wv.x; Ws[wk][wn+1]=wv.y; Ws[wk][wn+2]=wv.z; Ws[wk][wn+3]=wv.w;
    } else {
      #pragma unroll
      for (int j=0;j<4;j++)
        Ws[wk][wn+j] = (wcol+j < N) ? W[(size_t)(k0+wk)*N + wcol + j] : 0.f;
    }
    __syncthreads();
    #pragma unroll
    for (int k=0;k<BK;k++) {
      float4 a0 = *(const float4*)&As[k][ty*8];
      float4 a1 = *(const float4*)&As[k][ty*8+4];
      float4 b  = *(const float4*)&Ws[k][tx*4];
      float aa[8] = {a0.x,a0.y,a0.z,a0.w,a1.x,a1.y,a1.z,a1.w};
      float bb[4] = {b.x,b.y,b.z,b.w};
      #pragma unroll
      for (int i=0;i<8;i++)
        #pragma unroll
        for (int j=0;j<4;j++) acc[i][j] += aa[i]*bb[j];
    }
    __syncthreads();
  }

  #pragma unroll
  for (int j=0;j<4;j++) {
    int col = bn + tx*4 + j;
    if (col >= N) continue;
    float bv = (EPI>=1)? bias[col] : 0.f;
    #pragma unroll
    for (int i=0;i<8;i++) {
      int row = bm + ty*8 + i;
      float v = acc[i][j] + bv;
      if (EPI==2) v = gelu_f(v);
      Cout[(size_t)row*N + col] = v;
    }
  }
}

// ------------- depthwise causal conv(4) + bias + SiLU over xBC channels -------
__global__ __launch_bounds__(256)
void conv_silu(const float* __restrict__ zx, const float* __restrict__ cw,
               const float* __restrict__ cb, float* __restrict__ xbc)
{
  const int blk = blockIdx.x;           // b*SEQ + t
  const int t = blk & (SEQ-1);
  const size_t rowo = (size_t)blk * D_IN_PROJ + D_INNER;  // start of xBC slice
  #pragma unroll
  for (int it=0; it<5; ++it) {
    int c = it*256 + threadIdx.x;       // 0..1279
    float w0=cw[c*4+0], w1=cw[c*4+1], w2=cw[c*4+2], w3=cw[c*4+3];
    float acc = cb[c];
    if (t>=3) acc += w0 * zx[rowo - 3*(size_t)D_IN_PROJ + c];
    if (t>=2) acc += w1 * zx[rowo - 2*(size_t)D_IN_PROJ + c];
    if (t>=1) acc += w2 * zx[rowo - 1*(size_t)D_IN_PROJ + c];
    acc += w3 * zx[rowo + c];
    xbc[(size_t)blk*CONV_DIM + c] = acc * sigmoid_f(acc);
  }
}

// ---------------- dt = softplus(raw + bias), dA = exp(dt * -exp(A_log)) ------
__global__ __launch_bounds__(256)
void dt_kernel(const float* __restrict__ zx, const float* __restrict__ dt_bias,
               const float* __restrict__ A_log, float* __restrict__ dtp,
               float* __restrict__ dAv)
{
  int idx = blockIdx.x*256 + threadIdx.x;   // < NTOK*16
  int tok = idx >> 4, hh = idx & 15;
  float x = zx[(size_t)tok*D_IN_PROJ + (D_INNER + CONV_DIM) + hh] + dt_bias[hh];
  float sp = (x > 20.f) ? x : log1pf(expf(x));
  float A = -expf(A_log[hh]);
  dtp[idx] = sp;
  dAv[idx] = expf(sp * A);
}

// ---------------- sequential selective scan ----------------------------------
// grid: 256 blocks = (b, head, p-slice of 8). 256 threads:
//   pl = tid>>5 (p within slice), ng = tid&31, n = ng*4 .. +3 (4 state cols).
__global__ __launch_bounds__(256)
void scan_kernel(const float* __restrict__ xbc, const float* __restrict__ dtp,
                 const float* __restrict__ dAv, const float* __restrict__ D_skip,
                 float* __restrict__ y)
{
  const int blk = blockIdx.x;
  const int b  = blk >> 7;
  const int h  = (blk >> 3) & 15;
  const int sl = blk & 7;
  const int tid = threadIdx.x;
  const int pl = tid >> 5;
  const int p  = sl*8 + pl;
  const int ng = tid & 31;
  const int n0 = ng * 4;

  __shared__ float s_dt[SEQ];
  __shared__ float s_dA[SEQ];
  for (int i = tid; i < SEQ; i += 256) {
    s_dt[i] = dtp[((size_t)b*SEQ + i)*16 + h];
    s_dA[i] = dAv[((size_t)b*SEQ + i)*16 + h];
  }
  __syncthreads();

  const float dsk = D_skip[h];
  const float* base = xbc + (size_t)b*SEQ*CONV_DIM;
  float* ybase = y + (size_t)b*SEQ*D_INNER + h*HEADDIM + p;

  float h0=0.f,h1=0.f,h2=0.f,h3=0.f;
  #pragma unroll 4
  for (int t = 0; t < SEQ; ++t) {
    const float* row = base + (size_t)t*CONV_DIM;
    float xv = row[h*HEADDIM + p];
    float4 Bv = *(const float4*)(row + D_INNER + n0);
    float4 Cv = *(const float4*)(row + D_INNER + D_STATE + n0);
    float dt_t = s_dt[t], dA_t = s_dA[t];
    float dtx = dt_t * xv;
    h0 = h0*dA_t + dtx*Bv.x;
    h1 = h1*dA_t + dtx*Bv.y;
    h2 = h2*dA_t + dtx*Bv.z;
    h3 = h3*dA_t + dtx*Bv.w;
    float part = h0*Cv.x + h1*Cv.y + h2*Cv.z + h3*Cv.w;
    part += __shfl_xor(part, 16, 32);
    part += __shfl_xor(part,  8, 32);
    part += __shfl_xor(part,  4, 32);
    part += __shfl_xor(part,  2, 32);
    part += __shfl_xor(part,  1, 32);
    if (ng == 0) ybase[(size_t)t*D_INNER] = part + dsk * xv;
  }
}

// ---------------- y = y*silu(z); RMSNorm(1024)*gnorm_w (in place) ------------
__global__ __launch_bounds__(256)
void gate_rms(const float* __restrict__ zx, const float* __restrict__ gw,
              float* __restrict__ y)
{
  int tok = blockIdx.x;
  const float* z = zx + (size_t)tok*D_IN_PROJ;
  float* yr = y + (size_t)tok*D_INNER;
  float g[4];
  float ss = 0.f;
  #pragma unroll
  for (int i=0;i<4;i++) {
    int c = i*256 + threadIdx.x;
    float zv = z[c];
    float gv = yr[c] * (zv * sigmoid_f(zv));
    g[i]=gv; ss += gv*gv;
  }
  #pragma unroll
  for (int m=32;m>=1;m>>=1) ss += __shfl_xor(ss, m, 64);
  __shared__ float red[4];
  int wv = threadIdx.x >> 6;
  if ((threadIdx.x & 63)==0) red[wv]=ss;
  __syncthreads();
  float tot = red[0]+red[1]+red[2]+red[3];
  float sc = rsqrtf(tot*(1.f/1024.f) + 1e-5f);
  #pragma unroll
  for (int i=0;i<4;i++) {
    int c = i*256 + threadIdx.x;
    yr[c] = g[i]*sc*gw[c];
  }
}

// ---------------- out = LayerNorm(a + b) over 512, with gamma/beta -----------
__global__ __launch_bounds__(256)
void add_ln(const float* __restrict__ a, const float* __restrict__ bres,
            const float* __restrict__ gg, const float* __restrict__ bb,
            float* __restrict__ out)
{
  int tok = blockIdx.x;
  size_t o = (size_t)tok*D_MODEL;
  int c0 = threadIdx.x, c1 = threadIdx.x + 256;
  float v0 = a[o+c0] + bres[o+c0];
  float v1 = a[o+c1] + bres[o+c1];
  float s = v0+v1, sq = v0*v0+v1*v1;
  #pragma unroll
  for (int m=32;m>=1;m>>=1){ s += __shfl_xor(s,m,64); sq += __shfl_xor(sq,m,64); }
  __shared__ float rs[4], rq[4];
  int wv = threadIdx.x>>6;
  if ((threadIdx.x&63)==0){ rs[wv]=s; rq[wv]=sq; }
  __syncthreads();
  float S = rs[0]+rs[1]+rs[2]+rs[3];
  float Q = rq[0]+rq[1]+rq[2]+rq[3];
  float mean = S*(1.f/512.f);
  float var  = Q*(1.f/512.f) - mean*mean;
  float inv  = rsqrtf(var + 1e-5f);
  out[o+c0] = (v0-mean)*inv*gg[c0] + bb[c0];
  out[o+c1] = (v1-mean)*inv*gg[c1] + bb[c1];
}

extern "C" void kernel_launch(void* const* d_in, const int* in_sizes, int n_in,
                              void* d_out, int out_size, void* d_ws, size_t ws_size,
                              hipStream_t stream)
{
  const float* tgt    = (const float*)d_in[0];
  const float* W_in   = (const float*)d_in[1];
  const float* conv_w = (const float*)d_in[2];
  const float* conv_b = (const float*)d_in[3];
  const float* dt_bias= (const float*)d_in[4];
  const float* A_log  = (const float*)d_in[5];
  const float* D_skip = (const float*)d_in[6];
  const float* gnorm_w= (const float*)d_in[7];
  const float* W_out  = (const float*)d_in[8];
  const float* n1_g   = (const float*)d_in[9];
  const float* n1_b   = (const float*)d_in[10];
  const float* ffn_w1 = (const float*)d_in[11];
  const float* ffn_b1 = (const float*)d_in[12];
  const float* ffn_w2 = (const float*)d_in[13];
  const float* ffn_b2 = (const float*)d_in[14];
  const float* n3_g   = (const float*)d_in[15];
  const float* n3_b   = (const float*)d_in[16];
  float* out = (float*)d_out;
  float* ws  = (float*)d_ws;

  // workspace layout (floats); hmid aliases zx (zx is dead after gate_rms)
  float* zx   = ws;                              // NTOK*2320
  float* xbc  = zx  + (size_t)NTOK*D_IN_PROJ;    // NTOK*1280
  float* dtp  = xbc + (size_t)NTOK*CONV_DIM;     // NTOK*16
  float* dAv  = dtp + (size_t)NTOK*16;           // NTOK*16
  float* yb   = dAv + (size_t)NTOK*16;           // NTOK*1024
  float* tb   = yb  + (size_t)NTOK*D_INNER;      // NTOK*512
  float* tmp  = tb  + (size_t)NTOK*D_MODEL;      // NTOK*512
  float* hmid = zx;                              // NTOK*2048 (fits in zx's 2320)

  // 1) zxbcdt = tgt @ W_in   (4096 x 2320, K=512)
  gemm_f32<0><<<dim3((D_IN_PROJ+63)/64, NTOK/128), 256, 0, stream>>>(
      tgt, W_in, nullptr, zx, NTOK, D_IN_PROJ, D_MODEL);
  // 2) depthwise causal conv + SiLU
  conv_silu<<<NTOK, 256, 0, stream>>>(zx, conv_w, conv_b, xbc);
  // 3) dt / dA
  dt_kernel<<<(NTOK*16)/256, 256, 0, stream>>>(zx, dt_bias, A_log, dtp, dAv);
  // 4) selective scan (+ D_skip*x)
  scan_kernel<<<256, 256, 0, stream>>>(xbc, dtp, dAv, D_skip, yb);
  // 5) gate with silu(z) + RMSNorm * gnorm_w  (in place on yb)
  gate_rms<<<NTOK, 256, 0, stream>>>(zx, gnorm_w, yb);
  // 6) yb @ W_out -> tmp  (4096 x 512, K=1024)
  gemm_f32<0><<<dim3(D_MODEL/64, NTOK/128), 256, 0, stream>>>(
      yb, W_out, nullptr, tmp, NTOK, D_MODEL, D_INNER);
  // 7) tb = LayerNorm(tmp + tgt)
  add_ln<<<NTOK, 256, 0, stream>>>(tmp, tgt, n1_g, n1_b, tb);
  // 8) hmid = gelu(tb @ ffn_w1 + b1)  (4096 x 2048, K=512)
  gemm_f32<2><<<dim3(FF/64, NTOK/128), 256, 0, stream>>>(
      tb, ffn_w1, ffn_b1, hmid, NTOK, FF, D_MODEL);
  // 9) tmp = hmid @ ffn_w2 + b2  (4096 x 512, K=2048)
  gemm_f32<1><<<dim3(D_MODEL/64, NTOK/128), 256, 0, stream>>>(
      hmid, ffn_w2, ffn_b2, tmp, NTOK, D_MODEL, FF);
  // 10) out = LayerNorm(tmp + tb)
  add_ln<<<NTOK, 256, 0, stream>>>(tmp, tb, n3_g, n3_b, out);
}

// Round 2
// 840.289 us; speedup vs baseline: 1.7609x; 1.7609x over previous
//
#include <hip/hip_runtime.h>
#include <hip/hip_bf16.h>
#include <cstddef>

#define D_MODEL   512
#define FF        2048
#define D_STATE   128
#define D_INNER   1024
#define HEADDIM   64
#define NHEADS    16
#define CONV_DIM  1280
#define D_IN_PROJ 2320
#define B_SZ      2
#define SEQ       2048
#define NTOK      (B_SZ*SEQ)   // 4096
#define LCH       32
#define NCHUNK    (SEQ/LCH)    // 64
#define NCID      (B_SZ*NHEADS*NCHUNK)  // 2048

__device__ __forceinline__ float sigmoid_f(float x){ return 1.0f/(1.0f+expf(-x)); }
__device__ __forceinline__ float gelu_f(float x){ return 0.5f*x*(1.0f+erff(x*0.70710678118654752f)); }

// ---------------- fp32 GEMM: C = A(MxK) @ W(KxN) [+bias] [+gelu] --------------
template<int EPI>  // 0: none, 1: +bias, 2: gelu(.+bias)
__global__ __launch_bounds__(256)
void gemm_f32(const float* __restrict__ A, const float* __restrict__ W,
              const float* __restrict__ bias, float* __restrict__ Cout,
              int M, int N, int K)
{
  constexpr int BM=128, BN=64, BK=16;
  __shared__ float As[BK][BM+4];
  __shared__ float Ws[BK][BN+4];
  const int bm = blockIdx.y*BM, bn = blockIdx.x*BN;
  const int tid = threadIdx.x;
  const int tx = tid & 15, ty = tid >> 4;
  const int arow = tid >> 1;
  const int akc  = (tid & 1) * 8;
  const int wk   = tid >> 4;
  const int wn   = (tid & 15) * 4;

  float acc[8][4];
  #pragma unroll
  for (int i=0;i<8;i++)
    #pragma unroll
    for (int j=0;j<4;j++) acc[i][j]=0.f;

  const float* Arow = A + (size_t)(bm+arow)*K + akc;

  for (int k0=0; k0<K; k0+=BK) {
    float4 av0 = *(const float4*)(Arow + k0);
    float4 av1 = *(const float4*)(Arow + k0 + 4);
    As[akc+0][arow]=av0.x; As[akc+1][arow]=av0.y; As[akc+2][arow]=av0.z; As[akc+3][arow]=av0.w;
    As[akc+4][arow]=av1.x; As[akc+5][arow]=av1.y; As[akc+6][arow]=av1.z; As[akc+7][arow]=av1.w;
    const int wcol = bn + wn;
    if (wcol + 3 < N) {
      float4 wv = *(const float4*)(W + (size_t)(k0+wk)*N + wcol);
      Ws[wk][wn+0]=wv.x; Ws[wk][wn+1]=wv.y; Ws[wk][wn+2]=wv.z; Ws[wk][wn+3]=wv.w;
    } else {
      #pragma unroll
      for (int j=0;j<4;j++)
        Ws[wk][wn+j] = (wcol+j < N) ? W[(size_t)(k0+wk)*N + wcol + j] : 0.f;
    }
    __syncthreads();
    #pragma unroll
    for (int k=0;k<BK;k++) {
      float4 a0 = *(const float4*)&As[k][ty*8];
      float4 a1 = *(const float4*)&As[k][ty*8+4];
      float4 b  = *(const float4*)&Ws[k][tx*4];
      float aa[8] = {a0.x,a0.y,a0.z,a0.w,a1.x,a1.y,a1.z,a1.w};
      float bb[4] = {b.x,b.y,b.z,b.w};
      #pragma unroll
      for (int i=0;i<8;i++)
        #pragma unroll
        for (int j=0;j<4;j++) acc[i][j] += aa[i]*bb[j];
    }
    __syncthreads();
  }

  #pragma unroll
  for (int j=0;j<4;j++) {
    int col = bn + tx*4 + j;
    if (col >= N) continue;
    float bv = (EPI>=1)? bias[col] : 0.f;
    #pragma unroll
    for (int i=0;i<8;i++) {
      int row = bm + ty*8 + i;
      float v = acc[i][j] + bv;
      if (EPI==2) v = gelu_f(v);
      Cout[(size_t)row*N + col] = v;
    }
  }
}

// ------------- depthwise causal conv(4) + bias + SiLU over xBC channels -------
__global__ __launch_bounds__(256)
void conv_silu(const float* __restrict__ zx, const float* __restrict__ cw,
               const float* __restrict__ cb, float* __restrict__ xbc)
{
  const int blk = blockIdx.x;
  const int t = blk & (SEQ-1);
  const size_t rowo = (size_t)blk * D_IN_PROJ + D_INNER;
  #pragma unroll
  for (int it=0; it<5; ++it) {
    int c = it*256 + threadIdx.x;
    float w0=cw[c*4+0], w1=cw[c*4+1], w2=cw[c*4+2], w3=cw[c*4+3];
    float acc = cb[c];
    if (t>=3) acc += w0 * zx[rowo - 3*(size_t)D_IN_PROJ + c];
    if (t>=2) acc += w1 * zx[rowo - 2*(size_t)D_IN_PROJ + c];
    if (t>=1) acc += w2 * zx[rowo - 1*(size_t)D_IN_PROJ + c];
    acc += w3 * zx[rowo + c];
    xbc[(size_t)blk*CONV_DIM + c] = acc * sigmoid_f(acc);
  }
}

// ---------------- dt = softplus(raw + bias) ----------------------------------
__global__ __launch_bounds__(256)
void dt_kernel(const float* __restrict__ zx, const float* __restrict__ dt_bias,
               float* __restrict__ dtp)
{
  int idx = blockIdx.x*256 + threadIdx.x;   // < NTOK*16
  int tok = idx >> 4, hh = idx & 15;
  float x = zx[(size_t)tok*D_IN_PROJ + (D_INNER + CONV_DIM) + hh] + dt_bias[hh];
  float sp = (x > 20.f) ? x : log1pf(expf(x));
  dtp[idx] = sp;
}

// ============== chunked SSD scan ==============================================
// Kernel A: per (b,h,chunk): intra-chunk y + chunk-state S + log-cum buffers.
__global__ __launch_bounds__(256)
void chunk_intra(const float* __restrict__ xbc, const float* __restrict__ dtp,
                 const float* __restrict__ A_log, const float* __restrict__ D_skip,
                 float* __restrict__ y, __hip_bfloat16* __restrict__ Sbuf,
                 float* __restrict__ lcend, float* __restrict__ scl)
{
  __shared__ float Xt[LCH][HEADDIM+1];
  __shared__ float Bt[LCH][D_STATE+1];
  __shared__ float Ct[LCH][D_STATE+1];
  __shared__ float Mm[LCH][LCH+1];
  __shared__ float s_dt[LCH], s_lc[LCH], s_wend[LCH];

  const int cid = blockIdx.x;
  const int c  = cid & (NCHUNK-1);
  const int bh = cid >> 6;
  const int h  = bh & 15;
  const int b  = bh >> 4;
  const int tid = threadIdx.x;
  const int t0 = c*LCH;

  const float* rowbase = xbc + ((size_t)(b*SEQ + t0))*CONV_DIM;
  // load X tile (32x64): 512 float4, 2/thread
  #pragma unroll
  for (int u=0; u<2; ++u) {
    int q = tid*2+u;
    int r = q >> 4, c4 = (q & 15)*4;
    float4 v = *(const float4*)(rowbase + (size_t)r*CONV_DIM + h*HEADDIM + c4);
    Xt[r][c4]=v.x; Xt[r][c4+1]=v.y; Xt[r][c4+2]=v.z; Xt[r][c4+3]=v.w;
  }
  // load B,C tiles (32x128 each): 1024 float4 each, 4/thread
  #pragma unroll
  for (int u=0; u<4; ++u) {
    int q = tid*4+u;
    int r = q >> 5, c4 = (q & 31)*4;
    const float* rp = rowbase + (size_t)r*CONV_DIM + D_INNER;
    float4 v = *(const float4*)(rp + c4);
    Bt[r][c4]=v.x; Bt[r][c4+1]=v.y; Bt[r][c4+2]=v.z; Bt[r][c4+3]=v.w;
    float4 w = *(const float4*)(rp + D_STATE + c4);
    Ct[r][c4]=w.x; Ct[r][c4+1]=w.y; Ct[r][c4+2]=w.z; Ct[r][c4+3]=w.w;
  }
  // dt / log-cumsum (first 32 lanes of wave 0)
  if (tid < 32) {
    float A_h = -expf(A_log[h]);
    float dtv = dtp[((size_t)(b*SEQ + t0 + tid))*16 + h];
    float la = dtv * A_h;
    float lc = la;
    #pragma unroll
    for (int d=1; d<32; d<<=1) {
      float o = __shfl_up(lc, d, 32);
      if (tid >= d) lc += o;
    }
    float lc31 = __shfl(lc, 31, 32);
    s_dt[tid] = dtv;
    s_lc[tid] = lc;
    s_wend[tid] = expf(lc31 - lc) * dtv;
    scl[cid*LCH + tid] = expf(lc);
    if (tid == 31) lcend[cid] = lc;
  }
  __syncthreads();

  // M[i][j] = 1[j<=i]*exp(lc_i-lc_j)*dt_j*(C_i . B_j)
  {
    const int mi  = tid >> 3;
    const int mj0 = (tid & 7) * 4;
    float m0=0.f,m1=0.f,m2=0.f,m3=0.f;
    #pragma unroll 4
    for (int n=0;n<D_STATE;n++){
      float cv = Ct[mi][n];
      m0 += cv*Bt[mj0+0][n];
      m1 += cv*Bt[mj0+1][n];
      m2 += cv*Bt[mj0+2][n];
      m3 += cv*Bt[mj0+3][n];
    }
    float lci = s_lc[mi];
    float mv[4] = {m0,m1,m2,m3};
    #pragma unroll
    for (int q=0;q<4;q++){
      int j = mj0+q;
      Mm[mi][j] = (j <= mi) ? mv[q]*expf(lci - s_lc[j])*s_dt[j] : 0.f;
    }
  }
  __syncthreads();

  // y_intra = M@X + D*x
  const int p  = tid & 63;
  const int ig = tid >> 6;
  {
    const float dsk = D_skip[h];
    #pragma unroll
    for (int r=0;r<8;r++){
      int i = ig + r*4;
      float acc = dsk * Xt[i][p];
      #pragma unroll 4
      for (int j=0;j<LCH;j++) acc += Mm[i][j]*Xt[j][p];
      y[((size_t)(b*SEQ + t0 + i))*D_INNER + h*HEADDIM + p] = acc;
    }
  }
  __syncthreads();

  // scale X by wend[j], then S[n][p] = sum_j Bt[j][n]*Xw[j][p]
  #pragma unroll
  for (int u=0;u<8;u++){
    int q = tid + 256*u;
    int r = q>>6, pp = q&63;
    Xt[r][pp] *= s_wend[r];
  }
  __syncthreads();
  {
    __hip_bfloat16* Sout = Sbuf + (size_t)cid*(D_STATE*HEADDIM);
    #pragma unroll 4
    for (int r=0;r<32;r++){
      int n = ig + r*4;
      float acc=0.f;
      #pragma unroll 4
      for (int j=0;j<LCH;j++) acc += Bt[j][n]*Xt[j][p];
      Sout[n*HEADDIM + p] = __float2bfloat16(acc);
    }
  }
}

// Kernel B: serial inter-chunk state recurrence; overwrites S[c] with the state
// ENTERING chunk c (H_prev). 32 blocks, state in registers.
__global__ __launch_bounds__(256)
void state_scan(__hip_bfloat16* __restrict__ Sbuf, const float* __restrict__ lcend)
{
  const int bh = blockIdx.x;
  const int tid = threadIdx.x;
  float H[32];
  #pragma unroll
  for (int r=0;r<32;r++) H[r]=0.f;
  for (int c=0;c<NCHUNK;c++){
    const size_t base = ((size_t)(bh*NCHUNK + c))*(D_STATE*HEADDIM);
    float e = expf(lcend[bh*NCHUNK + c]);
    #pragma unroll
    for (int r=0;r<32;r++){
      size_t ix = base + tid + 256*r;
      float s = __bfloat162float(Sbuf[ix]);
      Sbuf[ix] = __float2bfloat16(H[r]);
      H[r] = e*H[r] + s;
    }
  }
}

// Kernel C: y += exp(lc_i) * C_i @ H_prev
__global__ __launch_bounds__(256)
void chunk_inter(const float* __restrict__ xbc, const __hip_bfloat16* __restrict__ Sbuf,
                 const float* __restrict__ scl, float* __restrict__ y)
{
  __shared__ float Ct[LCH][D_STATE+1];
  __shared__ float Hs[D_STATE][HEADDIM+1];
  const int cid = blockIdx.x;
  const int c  = cid & (NCHUNK-1);
  const int bh = cid >> 6;
  const int h  = bh & 15;
  const int b  = bh >> 4;
  const int tid = threadIdx.x;
  const int t0 = c*LCH;
  const float* rowbase = xbc + ((size_t)(b*SEQ + t0))*CONV_DIM;
  #pragma unroll
  for (int u=0;u<4;u++){
    int q = tid*4+u;
    int r = q>>5, c4 = (q&31)*4;
    float4 w = *(const float4*)(rowbase + (size_t)r*CONV_DIM + D_INNER + D_STATE + c4);
    Ct[r][c4]=w.x; Ct[r][c4+1]=w.y; Ct[r][c4+2]=w.z; Ct[r][c4+3]=w.w;
  }
  const __hip_bfloat16* Hin = Sbuf + (size_t)cid*(D_STATE*HEADDIM);
  #pragma unroll
  for (int u=0;u<32;u++){
    int q = tid + 256*u;
    Hs[q>>6][q&63] = __bfloat162float(Hin[q]);
  }
  __syncthreads();
  const int p = tid&63, ig = tid>>6;
  #pragma unroll
  for (int r=0;r<8;r++){
    int i = ig + r*4;
    float acc=0.f;
    #pragma unroll 4
    for (int n=0;n<D_STATE;n++) acc += Ct[i][n]*Hs[n][p];
    size_t yi = ((size_t)(b*SEQ + t0 + i))*D_INNER + h*HEADDIM + p;
    y[yi] += scl[cid*LCH + i] * acc;
  }
}

// ---------------- y = y*silu(z); RMSNorm(1024)*gnorm_w (in place) ------------
__global__ __launch_bounds__(256)
void gate_rms(const float* __restrict__ zx, const float* __restrict__ gw,
              float* __restrict__ y)
{
  int tok = blockIdx.x;
  const float* z = zx + (size_t)tok*D_IN_PROJ;
  float* yr = y + (size_t)tok*D_INNER;
  float g[4];
  float ss = 0.f;
  #pragma unroll
  for (int i=0;i<4;i++) {
    int c = i*256 + threadIdx.x;
    float zv = z[c];
    float gv = yr[c] * (zv * sigmoid_f(zv));
    g[i]=gv; ss += gv*gv;
  }
  #pragma unroll
  for (int m=32;m>=1;m>>=1) ss += __shfl_xor(ss, m, 64);
  __shared__ float red[4];
  int wv = threadIdx.x >> 6;
  if ((threadIdx.x & 63)==0) red[wv]=ss;
  __syncthreads();
  float tot = red[0]+red[1]+red[2]+red[3];
  float sc = rsqrtf(tot*(1.f/1024.f) + 1e-5f);
  #pragma unroll
  for (int i=0;i<4;i++) {
    int c = i*256 + threadIdx.x;
    yr[c] = g[i]*sc*gw[c];
  }
}

// ---------------- out = LayerNorm(a + b) over 512, with gamma/beta -----------
__global__ __launch_bounds__(256)
void add_ln(const float* __restrict__ a, const float* __restrict__ bres,
            const float* __restrict__ gg, const float* __restrict__ bb,
            float* __restrict__ out)
{
  int tok = blockIdx.x;
  size_t o = (size_t)tok*D_MODEL;
  int c0 = threadIdx.x, c1 = threadIdx.x + 256;
  float v0 = a[o+c0] + bres[o+c0];
  float v1 = a[o+c1] + bres[o+c1];
  float s = v0+v1, sq = v0*v0+v1*v1;
  #pragma unroll
  for (int m=32;m>=1;m>>=1){ s += __shfl_xor(s,m,64); sq += __shfl_xor(sq,m,64); }
  __shared__ float rs[4], rq[4];
  int wv = threadIdx.x>>6;
  if ((threadIdx.x&63)==0){ rs[wv]=s; rq[wv]=sq; }
  __syncthreads();
  float S = rs[0]+rs[1]+rs[2]+rs[3];
  float Q = rq[0]+rq[1]+rq[2]+rq[3];
  float mean = S*(1.f/512.f);
  float var  = Q*(1.f/512.f) - mean*mean;
  float inv  = rsqrtf(var + 1e-5f);
  out[o+c0] = (v0-mean)*inv*gg[c0] + bb[c0];
  out[o+c1] = (v1-mean)*inv*gg[c1] + bb[c1];
}

extern "C" void kernel_launch(void* const* d_in, const int* in_sizes, int n_in,
                              void* d_out, int out_size, void* d_ws, size_t ws_size,
                              hipStream_t stream)
{
  const float* tgt    = (const float*)d_in[0];
  const float* W_in   = (const float*)d_in[1];
  const float* conv_w = (const float*)d_in[2];
  const float* conv_b = (const float*)d_in[3];
  const float* dt_bias= (const float*)d_in[4];
  const float* A_log  = (const float*)d_in[5];
  const float* D_skip = (const float*)d_in[6];
  const float* gnorm_w= (const float*)d_in[7];
  const float* W_out  = (const float*)d_in[8];
  const float* n1_g   = (const float*)d_in[9];
  const float* n1_b   = (const float*)d_in[10];
  const float* ffn_w1 = (const float*)d_in[11];
  const float* ffn_b1 = (const float*)d_in[12];
  const float* ffn_w2 = (const float*)d_in[13];
  const float* ffn_b2 = (const float*)d_in[14];
  const float* n3_g   = (const float*)d_in[15];
  const float* n3_b   = (const float*)d_in[16];
  float* out = (float*)d_out;
  float* ws  = (float*)d_ws;

  // workspace layout (float offsets)
  float* zx   = ws;                                   // 9,502,720
  float* xbc  = zx  + (size_t)NTOK*D_IN_PROJ;         // 5,242,880
  float* dtp  = xbc + (size_t)NTOK*CONV_DIM;          // 65,536
  float* yb   = dtp + (size_t)NTOK*16;                // 4,194,304
  float* Sreg = yb  + (size_t)NTOK*D_INNER;           // S region: NCID*8192 bf16 = 8,388,608 floats
  __hip_bfloat16* Sbuf = (__hip_bfloat16*)Sreg;
  float* lcend= Sreg + (size_t)NCID*(D_STATE*HEADDIM)/2;  // 2048
  float* scl  = lcend + NCID;                         // 65,536
  // tb/tmp alias the S region (S dead before they're written)
  float* tb   = Sreg;                                 // NTOK*512
  float* tmp  = Sreg + (size_t)NTOK*D_MODEL;          // NTOK*512
  float* hmid = zx;                                   // NTOK*2048 fits in zx

  // 1) zxbcdt = tgt @ W_in
  gemm_f32<0><<<dim3((D_IN_PROJ+63)/64, NTOK/128), 256, 0, stream>>>(
      tgt, W_in, nullptr, zx, NTOK, D_IN_PROJ, D_MODEL);
  // 2) conv + SiLU
  conv_silu<<<NTOK, 256, 0, stream>>>(zx, conv_w, conv_b, xbc);
  // 3) dt
  dt_kernel<<<(NTOK*16)/256, 256, 0, stream>>>(zx, dt_bias, dtp);
  // 4) chunked scan: intra + state recurrence + inter
  chunk_intra<<<NCID, 256, 0, stream>>>(xbc, dtp, A_log, D_skip, yb, Sbuf, lcend, scl);
  state_scan<<<B_SZ*NHEADS, 256, 0, stream>>>(Sbuf, lcend);
  chunk_inter<<<NCID, 256, 0, stream>>>(xbc, Sbuf, scl, yb);
  // 5) gate + RMSNorm
  gate_rms<<<NTOK, 256, 0, stream>>>(zx, gnorm_w, yb);
  // 6) out-proj
  gemm_f32<0><<<dim3(D_MODEL/64, NTOK/128), 256, 0, stream>>>(
      yb, W_out, nullptr, tmp, NTOK, D_MODEL, D_INNER);
  // 7) tb = LayerNorm(tmp + tgt)
  add_ln<<<NTOK, 256, 0, stream>>>(tmp, tgt, n1_g, n1_b, tb);
  // 8) hmid = gelu(tb @ ffn_w1 + b1)
  gemm_f32<2><<<dim3(FF/64, NTOK/128), 256, 0, stream>>>(
      tb, ffn_w1, ffn_b1, hmid, NTOK, FF, D_MODEL);
  // 9) tmp = hmid @ ffn_w2 + b2
  gemm_f32<1><<<dim3(D_MODEL/64, NTOK/128), 256, 0, stream>>>(
      hmid, ffn_w2, ffn_b2, tmp, NTOK, D_MODEL, FF);
  // 10) out = LayerNorm(tmp + tb)
  add_ln<<<NTOK, 256, 0, stream>>>(tmp, tb, n3_g, n3_b, out);
}

// Round 3
// 391.932 us; speedup vs baseline: 3.7754x; 2.1440x over previous
//
#include <hip/hip_runtime.h>
#include <hip/hip_bf16.h>
#include <cstddef>
#include <cstdint>

#define D_MODEL   512
#define FF        2048
#define D_STATE   128
#define D_INNER   1024
#define HEADDIM   64
#define NHEADS    16
#define CONV_DIM  1280
#define D_IN_PROJ 2320
#define NPJ_PAD   2368      // D_IN_PROJ padded to 64
#define B_SZ      2
#define SEQ       2048
#define NTOK      (B_SZ*SEQ)   // 4096
#define LCH       32
#define NCHUNK    (SEQ/LCH)    // 64
#define NCID      (B_SZ*NHEADS*NCHUNK)  // 2048

typedef __attribute__((ext_vector_type(8))) short short8;
typedef __attribute__((ext_vector_type(4))) float f32x4;

__device__ __forceinline__ float sigmoid_f(float x){ return 1.0f/(1.0f+expf(-x)); }
__device__ __forceinline__ float gelu_f(float x){ return 0.5f*x*(1.0f+erff(x*0.70710678118654752f)); }

__device__ __forceinline__ void gload16(const void* g, void* l){
  __builtin_amdgcn_global_load_lds((const __attribute__((address_space(1))) void*)g,
                                   (__attribute__((address_space(3))) void*)l, 16, 0, 0);
}

// ============ bf16 MFMA GEMM: C(MxN) = A(MxK)bf16 @ Bt(N_pad x K)bf16^T ======
// BM=128, BN=64, BK=64. 256 threads = 4 waves, wave grid 2x2, each wave 64x32.
// LDS: As 128x64 bf16 (16KB) + Bs 64x64 bf16 (8KB), single buffer, 2 barriers.
// XOR swizzle ((row&7)<<4) applied on global source and on ds_read (rule #21).
template<int EPI, typename OT>   // EPI 0: none, 1: +bias, 2: gelu(.+bias)
__global__ __launch_bounds__(256)
void gemm_bf16(const __hip_bfloat16* __restrict__ A, const __hip_bfloat16* __restrict__ Bt,
               const float* __restrict__ bias, OT* __restrict__ C,
               int N, int K, int ldc)
{
  __shared__ char AsRaw[128*128];   // 128 rows x 128B (64 bf16)
  __shared__ char BsRaw[64*128];    //  64 rows x 128B

  const int t    = threadIdx.x;
  const int bm   = blockIdx.y * 128;
  const int bn   = blockIdx.x * 64;
  const int lane = t & 63;
  const int wid  = t >> 6;
  const int wr   = wid >> 1;        // 0..1 (64-row half)
  const int wc   = wid & 1;         // 0..1 (32-col half)
  const int lrow = lane & 15;
  const int lkb  = (lane >> 4) * 16;          // byte offset of lane's k-slice
  const int sw   = (lrow & 7) << 4;           // read-side XOR

  // staging addressing: pass u stages rows u*32..u*32+31; thread t -> row u*32+(t>>3)
  const int rA  = t >> 3;                     // 0..31
  const int cbA = (t & 7) * 16;
  const int scb = cbA ^ ((rA & 7) << 4);      // inverse-swizzled source col-byte
  const size_t strideA = (size_t)K * 2;
  const char* aSrc = (const char*)A  + (size_t)(bm + rA) * strideA + scb;
  const char* bSrc = (const char*)Bt + (size_t)(bn + rA) * strideA + scb;
  char* aDst = AsRaw + (t >> 6) * 1024;       // wave-uniform; HW adds lane*16
  char* bDst = BsRaw + (t >> 6) * 1024;

  f32x4 acc[4][2];
  #pragma unroll
  for (int m=0;m<4;m++)
    #pragma unroll
    for (int n=0;n<2;n++) acc[m][n] = (f32x4){0.f,0.f,0.f,0.f};

  const char* ArP = AsRaw + (wr*64 + lrow) * 128;
  const char* BrP = BsRaw + (wc*32 + lrow) * 128;

  for (int k0 = 0; k0 < K; k0 += 64) {
    const size_t ko = (size_t)k0 * 2;
    gload16(aSrc + ko,               aDst);
    gload16(aSrc + ko + 32*strideA,  aDst + 4096);
    gload16(aSrc + ko + 64*strideA,  aDst + 8192);
    gload16(aSrc + ko + 96*strideA,  aDst + 12288);
    gload16(bSrc + ko,               bDst);
    gload16(bSrc + ko + 32*strideA,  bDst + 4096);
    __syncthreads();
    #pragma unroll
    for (int kk = 0; kk < 2; ++kk) {
      const int kb = (kk*64 + lkb) ^ sw;
      short8 a0 = *(const short8*)(ArP + 0*2048 + kb);
      short8 a1 = *(const short8*)(ArP + 1*2048 + kb);
      short8 a2 = *(const short8*)(ArP + 2*2048 + kb);
      short8 a3 = *(const short8*)(ArP + 3*2048 + kb);
      short8 b0 = *(const short8*)(BrP + 0*2048 + kb);
      short8 b1 = *(const short8*)(BrP + 1*2048 + kb);
      acc[0][0] = __builtin_amdgcn_mfma_f32_16x16x32_bf16(a0, b0, acc[0][0], 0,0,0);
      acc[1][0] = __builtin_amdgcn_mfma_f32_16x16x32_bf16(a1, b0, acc[1][0], 0,0,0);
      acc[2][0] = __builtin_amdgcn_mfma_f32_16x16x32_bf16(a2, b0, acc[2][0], 0,0,0);
      acc[3][0] = __builtin_amdgcn_mfma_f32_16x16x32_bf16(a3, b0, acc[3][0], 0,0,0);
      acc[0][1] = __builtin_amdgcn_mfma_f32_16x16x32_bf16(a0, b1, acc[0][1], 0,0,0);
      acc[1][1] = __builtin_amdgcn_mfma_f32_16x16x32_bf16(a1, b1, acc[1][1], 0,0,0);
      acc[2][1] = __builtin_amdgcn_mfma_f32_16x16x32_bf16(a2, b1, acc[2][1], 0,0,0);
      acc[3][1] = __builtin_amdgcn_mfma_f32_16x16x32_bf16(a3, b1, acc[3][1], 0,0,0);
    }
    __syncthreads();
  }

  // epilogue: C/D layout col=lane&15, row=(lane>>4)*4+j  [m89-verified]
  const int orow0 = bm + wr*64 + (lane >> 4) * 4;
  const int ocol0 = bn + wc*32 + lrow;
  #pragma unroll
  for (int n=0;n<2;n++) {
    const int col = ocol0 + n*16;
    if (col >= N) continue;
    const float bv = (EPI>=1) ? bias[col] : 0.f;
    #pragma unroll
    for (int m=0;m<4;m++) {
      #pragma unroll
      for (int j=0;j<4;j++) {
        float v = acc[m][n][j] + bv;
        if (EPI==2) v = gelu_f(v);
        OT* cp = C + (size_t)(orow0 + m*16 + j)*ldc + col;
        if constexpr (sizeof(OT)==2) *cp = __float2bfloat16(v); else *cp = v;
      }
    }
  }
}

// ---- transpose fp32 [K][N] -> bf16 [Npad][K], rows >= N zero-padded ---------
__global__ __launch_bounds__(256)
void transpose_to_bf16(const float* __restrict__ in, __hip_bfloat16* __restrict__ out,
                       int K, int N, int Npad)
{
  __shared__ float tbuf[32][33];
  const int bx = blockIdx.x * 32;   // N dim
  const int by = blockIdx.y * 32;   // K dim
  const int tx = threadIdx.x & 31, ty = threadIdx.x >> 5;  // 32x8
  #pragma unroll
  for (int u=0;u<4;u++){
    int k = by + ty + u*8;
    int n = bx + tx;
    tbuf[ty+u*8][tx] = (n < N) ? in[(size_t)k*N + n] : 0.f;
  }
  __syncthreads();
  #pragma unroll
  for (int u=0;u<4;u++){
    int n = bx + ty + u*8;
    int k = by + tx;
    if (n < Npad) out[(size_t)n*K + k] = __float2bfloat16(tbuf[tx][ty+u*8]);
  }
}

// ---- flat fp32 -> bf16 convert ----------------------------------------------
__global__ __launch_bounds__(256)
void f32_to_bf16_k(const float* __restrict__ in, __hip_bfloat16* __restrict__ out, int n)
{
  int i = (blockIdx.x*256 + threadIdx.x)*4;
  if (i < n) {
    float4 v = *(const float4*)(in + i);
    out[i+0]=__float2bfloat16(v.x); out[i+1]=__float2bfloat16(v.y);
    out[i+2]=__float2bfloat16(v.z); out[i+3]=__float2bfloat16(v.w);
  }
}

// ------------- depthwise causal conv(4) + bias + SiLU over xBC channels -------
__global__ __launch_bounds__(256)
void conv_silu(const float* __restrict__ zx, const float* __restrict__ cw,
               const float* __restrict__ cb, float* __restrict__ xbc)
{
  const int blk = blockIdx.x;
  const int t = blk & (SEQ-1);
  const size_t rowo = (size_t)blk * D_IN_PROJ + D_INNER;
  #pragma unroll
  for (int it=0; it<5; ++it) {
    int c = it*256 + threadIdx.x;
    float w0=cw[c*4+0], w1=cw[c*4+1], w2=cw[c*4+2], w3=cw[c*4+3];
    float acc = cb[c];
    if (t>=3) acc += w0 * zx[rowo - 3*(size_t)D_IN_PROJ + c];
    if (t>=2) acc += w1 * zx[rowo - 2*(size_t)D_IN_PROJ + c];
    if (t>=1) acc += w2 * zx[rowo - 1*(size_t)D_IN_PROJ + c];
    acc += w3 * zx[rowo + c];
    xbc[(size_t)blk*CONV_DIM + c] = acc * sigmoid_f(acc);
  }
}

// ---------------- dt = softplus(raw + bias) ----------------------------------
__global__ __launch_bounds__(256)
void dt_kernel(const float* __restrict__ zx, const float* __restrict__ dt_bias,
               float* __restrict__ dtp)
{
  int idx = blockIdx.x*256 + threadIdx.x;   // < NTOK*16
  int tok = idx >> 4, hh = idx & 15;
  float x = zx[(size_t)tok*D_IN_PROJ + (D_INNER + CONV_DIM) + hh] + dt_bias[hh];
  float sp = (x > 20.f) ? x : log1pf(expf(x));
  dtp[idx] = sp;
}

// ============== chunked SSD scan ==============================================
__global__ __launch_bounds__(256)
void chunk_intra(const float* __restrict__ xbc, const float* __restrict__ dtp,
                 const float* __restrict__ A_log, const float* __restrict__ D_skip,
                 float* __restrict__ y, __hip_bfloat16* __restrict__ Sbuf,
                 float* __restrict__ lcend, float* __restrict__ scl)
{
  __shared__ float Xt[LCH][HEADDIM+1];
  __shared__ float Bt[LCH][D_STATE+1];
  __shared__ float Ct[LCH][D_STATE+1];
  __shared__ float Mm[LCH][LCH+1];
  __shared__ float s_dt[LCH], s_lc[LCH], s_wend[LCH];

  const int cid = blockIdx.x;
  const int c  = cid & (NCHUNK-1);
  const int bh = cid >> 6;
  const int h  = bh & 15;
  const int b  = bh >> 4;
  const int tid = threadIdx.x;
  const int t0 = c*LCH;

  const float* rowbase = xbc + ((size_t)(b*SEQ + t0))*CONV_DIM;
  #pragma unroll
  for (int u=0; u<2; ++u) {
    int q = tid*2+u;
    int r = q >> 4, c4 = (q & 15)*4;
    float4 v = *(const float4*)(rowbase + (size_t)r*CONV_DIM + h*HEADDIM + c4);
    Xt[r][c4]=v.x; Xt[r][c4+1]=v.y; Xt[r][c4+2]=v.z; Xt[r][c4+3]=v.w;
  }
  #pragma unroll
  for (int u=0; u<4; ++u) {
    int q = tid*4+u;
    int r = q >> 5, c4 = (q & 31)*4;
    const float* rp = rowbase + (size_t)r*CONV_DIM + D_INNER;
    float4 v = *(const float4*)(rp + c4);
    Bt[r][c4]=v.x; Bt[r][c4+1]=v.y; Bt[r][c4+2]=v.z; Bt[r][c4+3]=v.w;
    float4 w = *(const float4*)(rp + D_STATE + c4);
    Ct[r][c4]=w.x; Ct[r][c4+1]=w.y; Ct[r][c4+2]=w.z; Ct[r][c4+3]=w.w;
  }
  if (tid < 32) {
    float A_h = -expf(A_log[h]);
    float dtv = dtp[((size_t)(b*SEQ + t0 + tid))*16 + h];
    float la = dtv * A_h;
    float lc = la;
    #pragma unroll
    for (int d=1; d<32; d<<=1) {
      float o = __shfl_up(lc, d, 32);
      if (tid >= d) lc += o;
    }
    float lc31 = __shfl(lc, 31, 32);
    s_dt[tid] = dtv;
    s_lc[tid] = lc;
    s_wend[tid] = expf(lc31 - lc) * dtv;
    scl[cid*LCH + tid] = expf(lc);
    if (tid == 31) lcend[cid] = lc;
  }
  __syncthreads();

  {
    const int mi  = tid >> 3;
    const int mj0 = (tid & 7) * 4;
    float m0=0.f,m1=0.f,m2=0.f,m3=0.f;
    #pragma unroll 4
    for (int n=0;n<D_STATE;n++){
      float cv = Ct[mi][n];
      m0 += cv*Bt[mj0+0][n];
      m1 += cv*Bt[mj0+1][n];
      m2 += cv*Bt[mj0+2][n];
      m3 += cv*Bt[mj0+3][n];
    }
    float lci = s_lc[mi];
    float mv[4] = {m0,m1,m2,m3};
    #pragma unroll
    for (int q=0;q<4;q++){
      int j = mj0+q;
      Mm[mi][j] = (j <= mi) ? mv[q]*expf(lci - s_lc[j])*s_dt[j] : 0.f;
    }
  }
  __syncthreads();

  const int p  = tid & 63;
  const int ig = tid >> 6;
  {
    const float dsk = D_skip[h];
    #pragma unroll
    for (int r=0;r<8;r++){
      int i = ig + r*4;
      float acc = dsk * Xt[i][p];
      #pragma unroll 4
      for (int j=0;j<LCH;j++) acc += Mm[i][j]*Xt[j][p];
      y[((size_t)(b*SEQ + t0 + i))*D_INNER + h*HEADDIM + p] = acc;
    }
  }
  __syncthreads();

  #pragma unroll
  for (int u=0;u<8;u++){
    int q = tid + 256*u;
    int r = q>>6, pp = q&63;
    Xt[r][pp] *= s_wend[r];
  }
  __syncthreads();
  {
    __hip_bfloat16* Sout = Sbuf + (size_t)cid*(D_STATE*HEADDIM);
    #pragma unroll 4
    for (int r=0;r<32;r++){
      int n = ig + r*4;
      float acc=0.f;
      #pragma unroll 4
      for (int j=0;j<LCH;j++) acc += Bt[j][n]*Xt[j][p];
      Sout[n*HEADDIM + p] = __float2bfloat16(acc);
    }
  }
}

__global__ __launch_bounds__(256)
void state_scan(__hip_bfloat16* __restrict__ Sbuf, const float* __restrict__ lcend)
{
  const int bh = blockIdx.x;
  const int tid = threadIdx.x;
  float H[32];
  #pragma unroll
  for (int r=0;r<32;r++) H[r]=0.f;
  for (int c=0;c<NCHUNK;c++){
    const size_t base = ((size_t)(bh*NCHUNK + c))*(D_STATE*HEADDIM);
    float e = expf(lcend[bh*NCHUNK + c]);
    #pragma unroll
    for (int r=0;r<32;r++){
      size_t ix = base + tid + 256*r;
      float s = __bfloat162float(Sbuf[ix]);
      Sbuf[ix] = __float2bfloat16(H[r]);
      H[r] = e*H[r] + s;
    }
  }
}

__global__ __launch_bounds__(256)
void chunk_inter(const float* __restrict__ xbc, const __hip_bfloat16* __restrict__ Sbuf,
                 const float* __restrict__ scl, float* __restrict__ y)
{
  __shared__ float Ct[LCH][D_STATE+1];
  __shared__ float Hs[D_STATE][HEADDIM+1];
  const int cid = blockIdx.x;
  const int c  = cid & (NCHUNK-1);
  const int bh = cid >> 6;
  const int h  = bh & 15;
  const int b  = bh >> 4;
  const int tid = threadIdx.x;
  const int t0 = c*LCH;
  const float* rowbase = xbc + ((size_t)(b*SEQ + t0))*CONV_DIM;
  #pragma unroll
  for (int u=0;u<4;u++){
    int q = tid*4+u;
    int r = q>>5, c4 = (q&31)*4;
    float4 w = *(const float4*)(rowbase + (size_t)r*CONV_DIM + D_INNER + D_STATE + c4);
    Ct[r][c4]=w.x; Ct[r][c4+1]=w.y; Ct[r][c4+2]=w.z; Ct[r][c4+3]=w.w;
  }
  const __hip_bfloat16* Hin = Sbuf + (size_t)cid*(D_STATE*HEADDIM);
  #pragma unroll
  for (int u=0;u<32;u++){
    int q = tid + 256*u;
    Hs[q>>6][q&63] = __bfloat162float(Hin[q]);
  }
  __syncthreads();
  const int p = tid&63, ig = tid>>6;
  #pragma unroll
  for (int r=0;r<8;r++){
    int i = ig + r*4;
    float acc=0.f;
    #pragma unroll 4
    for (int n=0;n<D_STATE;n++) acc += Ct[i][n]*Hs[n][p];
    size_t yi = ((size_t)(b*SEQ + t0 + i))*D_INNER + h*HEADDIM + p;
    y[yi] += scl[cid*LCH + i] * acc;
  }
}

// -------- y*silu(z), RMSNorm(1024)*gnorm_w -> bf16 out -----------------------
__global__ __launch_bounds__(256)
void gate_rms(const float* __restrict__ zx, const float* __restrict__ gw,
              const float* __restrict__ yin, __hip_bfloat16* __restrict__ ybf)
{
  int tok = blockIdx.x;
  const float* z = zx + (size_t)tok*D_IN_PROJ;
  const float* yr = yin + (size_t)tok*D_INNER;
  __hip_bfloat16* yo = ybf + (size_t)tok*D_INNER;
  float g[4];
  float ss = 0.f;
  #pragma unroll
  for (int i=0;i<4;i++) {
    int c = i*256 + threadIdx.x;
    float zv = z[c];
    float gv = yr[c] * (zv * sigmoid_f(zv));
    g[i]=gv; ss += gv*gv;
  }
  #pragma unroll
  for (int m=32;m>=1;m>>=1) ss += __shfl_xor(ss, m, 64);
  __shared__ float red[4];
  int wv = threadIdx.x >> 6;
  if ((threadIdx.x & 63)==0) red[wv]=ss;
  __syncthreads();
  float tot = red[0]+red[1]+red[2]+red[3];
  float sc = rsqrtf(tot*(1.f/1024.f) + 1e-5f);
  #pragma unroll
  for (int i=0;i<4;i++) {
    int c = i*256 + threadIdx.x;
    yo[c] = __float2bfloat16(g[i]*sc*gw[c]);
  }
}

// ---------------- out = LayerNorm(a + b); optional bf16 copy -----------------
template<int WBF>
__global__ __launch_bounds__(256)
void add_ln(const float* __restrict__ a, const float* __restrict__ bres,
            const float* __restrict__ gg, const float* __restrict__ bb,
            float* __restrict__ out, __hip_bfloat16* __restrict__ outbf)
{
  int tok = blockIdx.x;
  size_t o = (size_t)tok*D_MODEL;
  int c0 = threadIdx.x, c1 = threadIdx.x + 256;
  float v0 = a[o+c0] + bres[o+c0];
  float v1 = a[o+c1] + bres[o+c1];
  float s = v0+v1, sq = v0*v0+v1*v1;
  #pragma unroll
  for (int m=32;m>=1;m>>=1){ s += __shfl_xor(s,m,64); sq += __shfl_xor(sq,m,64); }
  __shared__ float rs[4], rq[4];
  int wv = threadIdx.x>>6;
  if ((threadIdx.x&63)==0){ rs[wv]=s; rq[wv]=sq; }
  __syncthreads();
  float S = rs[0]+rs[1]+rs[2]+rs[3];
  float Q = rq[0]+rq[1]+rq[2]+rq[3];
  float mean = S*(1.f/512.f);
  float var  = Q*(1.f/512.f) - mean*mean;
  float inv  = rsqrtf(var + 1e-5f);
  float o0 = (v0-mean)*inv*gg[c0] + bb[c0];
  float o1 = (v1-mean)*inv*gg[c1] + bb[c1];
  out[o+c0] = o0;
  out[o+c1] = o1;
  if (WBF) { outbf[o+c0] = __float2bfloat16(o0); outbf[o+c1] = __float2bfloat16(o1); }
}

extern "C" void kernel_launch(void* const* d_in, const int* in_sizes, int n_in,
                              void* d_out, int out_size, void* d_ws, size_t ws_size,
                              hipStream_t stream)
{
  const float* tgt    = (const float*)d_in[0];
  const float* W_in   = (const float*)d_in[1];
  const float* conv_w = (const float*)d_in[2];
  const float* conv_b = (const float*)d_in[3];
  const float* dt_bias= (const float*)d_in[4];
  const float* A_log  = (const float*)d_in[5];
  const float* D_skip = (const float*)d_in[6];
  const float* gnorm_w= (const float*)d_in[7];
  const float* W_out  = (const float*)d_in[8];
  const float* n1_g   = (const float*)d_in[9];
  const float* n1_b   = (const float*)d_in[10];
  const float* ffn_w1 = (const float*)d_in[11];
  const float* ffn_b1 = (const float*)d_in[12];
  const float* ffn_w2 = (const float*)d_in[13];
  const float* ffn_b2 = (const float*)d_in[14];
  const float* n3_g   = (const float*)d_in[15];
  const float* n3_b   = (const float*)d_in[16];
  float* out = (float*)d_out;
  float* ws  = (float*)d_ws;

  // ---- workspace layout (float offsets), total ~27.5M floats (~110 MB) -----
  float* zx   = ws;                                   // 9,502,720
  float* xbc  = zx  + (size_t)NTOK*D_IN_PROJ;         // 5,242,880
  float* dtp  = xbc + (size_t)NTOK*CONV_DIM;          // 65,536
  float* yb   = dtp + (size_t)NTOK*16;                // 4,194,304
  float* Sreg = yb  + (size_t)NTOK*D_INNER;           // 8,388,608 (Sbuf bf16)
  __hip_bfloat16* Sbuf = (__hip_bfloat16*)Sreg;
  float* lcend= Sreg + (size_t)NCID*(D_STATE*HEADDIM)/2;
  float* scl  = lcend + NCID;

  // aliases into dead regions:
  __hip_bfloat16* tgt_bf = (__hip_bfloat16*)yb;               // used step 1 only
  __hip_bfloat16* Wint   = (__hip_bfloat16*)Sreg;             // [2368][512], used step 1
  __hip_bfloat16* yb_bf  = (__hip_bfloat16*)xbc;              // xbc dead after chunk_inter
  __hip_bfloat16* tb_bf  = (__hip_bfloat16*)(xbc + 2097152);
  float* tb   = Sreg;                                         // Sbuf dead after chunk_inter
  float* tmp  = Sreg + 2097152;
  __hip_bfloat16* Woutt  = (__hip_bfloat16*)(Sreg + 4194304); // [512][1024]
  __hip_bfloat16* W1t    = (__hip_bfloat16*)(Sreg + 4194304 + 262144);   // [2048][512]
  __hip_bfloat16* W2t    = (__hip_bfloat16*)(Sreg + 4194304 + 262144 + 524288); // [512][2048]
  __hip_bfloat16* hmid_bf= (__hip_bfloat16*)zx;               // zx dead after gate_rms

  // 0) W_in transpose->bf16 (into Sreg, dead until chunk_intra) + tgt->bf16
  transpose_to_bf16<<<dim3(NPJ_PAD/32, D_MODEL/32), 256, 0, stream>>>(W_in, Wint, D_MODEL, D_IN_PROJ, NPJ_PAD);
  f32_to_bf16_k<<<(NTOK*D_MODEL)/1024, 256, 0, stream>>>(tgt, tgt_bf, NTOK*D_MODEL);
  // 1) zxbcdt = tgt @ W_in   (MFMA)
  gemm_bf16<0,float><<<dim3(NPJ_PAD/64, NTOK/128), 256, 0, stream>>>(
      tgt_bf, Wint, nullptr, zx, D_IN_PROJ, D_MODEL, D_IN_PROJ);
  // 2) conv + SiLU
  conv_silu<<<NTOK, 256, 0, stream>>>(zx, conv_w, conv_b, xbc);
  // 3) dt
  dt_kernel<<<(NTOK*16)/256, 256, 0, stream>>>(zx, dt_bias, dtp);
  // 4) chunked scan
  chunk_intra<<<NCID, 256, 0, stream>>>(xbc, dtp, A_log, D_skip, yb, Sbuf, lcend, scl);
  state_scan<<<B_SZ*NHEADS, 256, 0, stream>>>(Sbuf, lcend);
  chunk_inter<<<NCID, 256, 0, stream>>>(xbc, Sbuf, scl, yb);
  // 4d) remaining weight transposes (Sbuf now dead; regions beyond tb/tmp)
  transpose_to_bf16<<<dim3(D_MODEL/32, D_INNER/32), 256, 0, stream>>>(W_out, Woutt, D_INNER, D_MODEL, D_MODEL);
  transpose_to_bf16<<<dim3(FF/32, D_MODEL/32), 256, 0, stream>>>(ffn_w1, W1t, D_MODEL, FF, FF);
  transpose_to_bf16<<<dim3(D_MODEL/32, FF/32), 256, 0, stream>>>(ffn_w2, W2t, FF, D_MODEL, D_MODEL);
  // 5) gate + RMSNorm -> bf16
  gate_rms<<<NTOK, 256, 0, stream>>>(zx, gnorm_w, yb, yb_bf);
  // 6) out-proj (MFMA): tmp = yb @ W_out
  gemm_bf16<0,float><<<dim3(D_MODEL/64, NTOK/128), 256, 0, stream>>>(
      yb_bf, Woutt, nullptr, tmp, D_MODEL, D_INNER, D_MODEL);
  // 7) tb = LayerNorm(tmp + tgt)  (+ bf16 copy)
  add_ln<1><<<NTOK, 256, 0, stream>>>(tmp, tgt, n1_g, n1_b, tb, tb_bf);
  // 8) hmid = gelu(tb @ ffn_w1 + b1) -> bf16 (MFMA)
  gemm_bf16<2,__hip_bfloat16><<<dim3(FF/64, NTOK/128), 256, 0, stream>>>(
      tb_bf, W1t, ffn_b1, hmid_bf, FF, D_MODEL, FF);
  // 9) tmp = hmid @ ffn_w2 + b2 (MFMA)
  gemm_bf16<1,float><<<dim3(D_MODEL/64, NTOK/128), 256, 0, stream>>>(
      hmid_bf, W2t, ffn_b2, tmp, D_MODEL, FF, D_MODEL);
  // 10) out = LayerNorm(tmp + tb)
  add_ln<0><<<NTOK, 256, 0, stream>>>(tmp, tb, n3_g, n3_b, out, nullptr);
}

// Round 4
// 241.784 us; speedup vs baseline: 6.1199x; 1.6210x over previous
//
#include <hip/hip_runtime.h>
#include <hip/hip_bf16.h>
#include <cstddef>
#include <cstdint>

#define D_MODEL   512
#define FF        2048
#define D_STATE   128
#define D_INNER   1024
#define HEADDIM   64
#define NHEADS    16
#define CONV_DIM  1280
#define D_IN_PROJ 2320
#define NPJ_PAD   2368      // D_IN_PROJ padded to 64
#define B_SZ      2
#define SEQ       2048
#define NTOK      (B_SZ*SEQ)   // 4096
#define LCH       32
#define NCHUNK    (SEQ/LCH)    // 64
#define NCID      (B_SZ*NHEADS*NCHUNK)  // 2048

typedef __attribute__((ext_vector_type(8))) short short8;
typedef __attribute__((ext_vector_type(4))) float f32x4;

__device__ __forceinline__ float sigmoid_f(float x){ return 1.0f/(1.0f+expf(-x)); }
__device__ __forceinline__ float gelu_f(float x){ return 0.5f*x*(1.0f+erff(x*0.70710678118654752f)); }

__device__ __forceinline__ unsigned short bf16bits(float f){
  __hip_bfloat16 h = __float2bfloat16(f);
  return *reinterpret_cast<unsigned short*>(&h);
}
__device__ __forceinline__ float blo(unsigned u){ return __uint_as_float(u<<16); }
__device__ __forceinline__ float bhi(unsigned u){ return __uint_as_float(u & 0xffff0000u); }
__device__ __forceinline__ unsigned bfpack2(float a, float b){
  return (unsigned)bf16bits(a) | ((unsigned)bf16bits(b)<<16);
}

__device__ __forceinline__ void gload16(const void* g, void* l){
  __builtin_amdgcn_global_load_lds((const __attribute__((address_space(1))) void*)g,
                                   (__attribute__((address_space(3))) void*)l, 16, 0, 0);
}

// ============ bf16 MFMA GEMM: C(MxN) = A(MxK)bf16 @ Bt(N_pad x K)bf16^T ======
template<int EPI, typename OT>   // EPI 0: none, 1: +bias, 2: gelu(.+bias)
__global__ __launch_bounds__(256)
void gemm_bf16(const __hip_bfloat16* __restrict__ A, const __hip_bfloat16* __restrict__ Bt,
               const float* __restrict__ bias, OT* __restrict__ C,
               int N, int K, int ldc)
{
  __shared__ char AsRaw[128*128];
  __shared__ char BsRaw[64*128];

  const int t    = threadIdx.x;
  const int bm   = blockIdx.y * 128;
  const int bn   = blockIdx.x * 64;
  const int lane = t & 63;
  const int wid  = t >> 6;
  const int wr   = wid >> 1;
  const int wc   = wid & 1;
  const int lrow = lane & 15;
  const int lkb  = (lane >> 4) * 16;
  const int sw   = (lrow & 7) << 4;

  const int rA  = t >> 3;
  const int cbA = (t & 7) * 16;
  const int scb = cbA ^ ((rA & 7) << 4);
  const size_t strideA = (size_t)K * 2;
  const char* aSrc = (const char*)A  + (size_t)(bm + rA) * strideA + scb;
  const char* bSrc = (const char*)Bt + (size_t)(bn + rA) * strideA + scb;
  char* aDst = AsRaw + (t >> 6) * 1024;
  char* bDst = BsRaw + (t >> 6) * 1024;

  f32x4 acc[4][2];
  #pragma unroll
  for (int m=0;m<4;m++)
    #pragma unroll
    for (int n=0;n<2;n++) acc[m][n] = (f32x4){0.f,0.f,0.f,0.f};

  const char* ArP = AsRaw + (wr*64 + lrow) * 128;
  const char* BrP = BsRaw + (wc*32 + lrow) * 128;

  for (int k0 = 0; k0 < K; k0 += 64) {
    const size_t ko = (size_t)k0 * 2;
    gload16(aSrc + ko,               aDst);
    gload16(aSrc + ko + 32*strideA,  aDst + 4096);
    gload16(aSrc + ko + 64*strideA,  aDst + 8192);
    gload16(aSrc + ko + 96*strideA,  aDst + 12288);
    gload16(bSrc + ko,               bDst);
    gload16(bSrc + ko + 32*strideA,  bDst + 4096);
    __syncthreads();
    #pragma unroll
    for (int kk = 0; kk < 2; ++kk) {
      const int kb = (kk*64 + lkb) ^ sw;
      short8 a0 = *(const short8*)(ArP + 0*2048 + kb);
      short8 a1 = *(const short8*)(ArP + 1*2048 + kb);
      short8 a2 = *(const short8*)(ArP + 2*2048 + kb);
      short8 a3 = *(const short8*)(ArP + 3*2048 + kb);
      short8 b0 = *(const short8*)(BrP + 0*2048 + kb);
      short8 b1 = *(const short8*)(BrP + 1*2048 + kb);
      acc[0][0] = __builtin_amdgcn_mfma_f32_16x16x32_bf16(a0, b0, acc[0][0], 0,0,0);
      acc[1][0] = __builtin_amdgcn_mfma_f32_16x16x32_bf16(a1, b0, acc[1][0], 0,0,0);
      acc[2][0] = __builtin_amdgcn_mfma_f32_16x16x32_bf16(a2, b0, acc[2][0], 0,0,0);
      acc[3][0] = __builtin_amdgcn_mfma_f32_16x16x32_bf16(a3, b0, acc[3][0], 0,0,0);
      acc[0][1] = __builtin_amdgcn_mfma_f32_16x16x32_bf16(a0, b1, acc[0][1], 0,0,0);
      acc[1][1] = __builtin_amdgcn_mfma_f32_16x16x32_bf16(a1, b1, acc[1][1], 0,0,0);
      acc[2][1] = __builtin_amdgcn_mfma_f32_16x16x32_bf16(a2, b1, acc[2][1], 0,0,0);
      acc[3][1] = __builtin_amdgcn_mfma_f32_16x16x32_bf16(a3, b1, acc[3][1], 0,0,0);
    }
    __syncthreads();
  }

  const int orow0 = bm + wr*64 + (lane >> 4) * 4;
  const int ocol0 = bn + wc*32 + lrow;
  #pragma unroll
  for (int n=0;n<2;n++) {
    const int col = ocol0 + n*16;
    if (col >= N) continue;
    const float bv = (EPI>=1) ? bias[col] : 0.f;
    #pragma unroll
    for (int m=0;m<4;m++) {
      #pragma unroll
      for (int j=0;j<4;j++) {
        float v = acc[m][n][j] + bv;
        if (EPI==2) v = gelu_f(v);
        OT* cp = C + (size_t)(orow0 + m*16 + j)*ldc + col;
        if constexpr (sizeof(OT)==2) *cp = __float2bfloat16(v); else *cp = v;
      }
    }
  }
}

// ---- transpose fp32 [K][N] -> bf16 [Npad][K] --------------------------------
__global__ __launch_bounds__(256)
void transpose_to_bf16(const float* __restrict__ in, __hip_bfloat16* __restrict__ out,
                       int K, int N, int Npad)
{
  __shared__ float tbuf[32][33];
  const int bx = blockIdx.x * 32;
  const int by = blockIdx.y * 32;
  const int tx = threadIdx.x & 31, ty = threadIdx.x >> 5;
  #pragma unroll
  for (int u=0;u<4;u++){
    int k = by + ty + u*8;
    int n = bx + tx;
    tbuf[ty+u*8][tx] = (n < N) ? in[(size_t)k*N + n] : 0.f;
  }
  __syncthreads();
  #pragma unroll
  for (int u=0;u<4;u++){
    int n = bx + ty + u*8;
    int k = by + tx;
    if (n < Npad) out[(size_t)n*K + k] = __float2bfloat16(tbuf[tx][ty+u*8]);
  }
}

__global__ __launch_bounds__(256)
void f32_to_bf16_k(const float* __restrict__ in, __hip_bfloat16* __restrict__ out, int n)
{
  int i = (blockIdx.x*256 + threadIdx.x)*4;
  if (i < n) {
    float4 v = *(const float4*)(in + i);
    out[i+0]=__float2bfloat16(v.x); out[i+1]=__float2bfloat16(v.y);
    out[i+2]=__float2bfloat16(v.z); out[i+3]=__float2bfloat16(v.w);
  }
}

// ------- depthwise causal conv(4)+SiLU, sliding-window registers -------------
// grid: (1280/256, SEQ/64, B). Thread owns one channel, walks 64 t's.
__global__ __launch_bounds__(256)
void conv_silu(const float* __restrict__ zx, const float* __restrict__ cw,
               const float* __restrict__ cb, float* __restrict__ xbc)
{
  const int c  = blockIdx.x*256 + threadIdx.x;     // 0..1279
  const int t0 = blockIdx.y*64;
  const int b  = blockIdx.z;
  const float w0=cw[c*4+0], w1=cw[c*4+1], w2=cw[c*4+2], w3=cw[c*4+3];
  const float cbv = cb[c];
  const float* base = zx + ((size_t)(b*SEQ + t0))*D_IN_PROJ + D_INNER + c;
  float* obase = xbc + ((size_t)(b*SEQ + t0))*CONV_DIM + c;
  float xm3, xm2, xm1;
  if (t0 == 0) { xm3 = 0.f; xm2 = 0.f; xm1 = 0.f; }
  else {
    xm3 = base[-3*(ptrdiff_t)D_IN_PROJ];
    xm2 = base[-2*(ptrdiff_t)D_IN_PROJ];
    xm1 = base[-1*(ptrdiff_t)D_IN_PROJ];
  }
  #pragma unroll 4
  for (int t=0; t<64; ++t) {
    float xc = base[(size_t)t*D_IN_PROJ];
    float acc = cbv + w0*xm3 + w1*xm2 + w2*xm1 + w3*xc;
    obase[(size_t)t*CONV_DIM] = acc * sigmoid_f(acc);
    xm3 = xm2; xm2 = xm1; xm1 = xc;
  }
}

// ---------------- dt = softplus(raw + bias) ----------------------------------
__global__ __launch_bounds__(256)
void dt_kernel(const float* __restrict__ zx, const float* __restrict__ dt_bias,
               float* __restrict__ dtp)
{
  int idx = blockIdx.x*256 + threadIdx.x;
  int tok = idx >> 4, hh = idx & 15;
  float x = zx[(size_t)tok*D_IN_PROJ + (D_INNER + CONV_DIM) + hh] + dt_bias[hh];
  float sp = (x > 20.f) ? x : log1pf(expf(x));
  dtp[idx] = sp;
}

// ============== chunked SSD scan (register-tiled) =============================
#define XP (HEADDIM+4)    // 68: 16B-aligned stride
#define SP (D_STATE+12)   // 140: 16B-aligned, word-stride 3 mod 32

__global__ __launch_bounds__(256)
void chunk_intra(const float* __restrict__ xbc, const float* __restrict__ dtp,
                 const float* __restrict__ A_log, const float* __restrict__ D_skip,
                 float* __restrict__ y, __hip_bfloat16* __restrict__ Sbuf,
                 float* __restrict__ lcend, float* __restrict__ scl)
{
  __shared__ float Xt[LCH][XP];
  __shared__ float Bt[LCH][SP];
  __shared__ float Ct[LCH][SP];
  __shared__ float Mm[LCH][LCH+1];
  __shared__ float s_dt[LCH], s_lc[LCH], s_wend[LCH];

  const int cid = blockIdx.x;
  const int c  = cid & (NCHUNK-1);
  const int bh = cid >> 6;
  const int h  = bh & 15;
  const int b  = bh >> 4;
  const int tid = threadIdx.x;
  const int t0 = c*LCH;

  const float* rowbase = xbc + ((size_t)(b*SEQ + t0))*CONV_DIM;
  #pragma unroll
  for (int u=0; u<2; ++u) {
    int q = tid*2+u;
    int r = q >> 4, c4 = (q & 15)*4;
    float4 v = *(const float4*)(rowbase + (size_t)r*CONV_DIM + h*HEADDIM + c4);
    *(float4*)&Xt[r][c4] = v;
  }
  #pragma unroll
  for (int u=0; u<4; ++u) {
    int q = tid*4+u;
    int r = q >> 5, c4 = (q & 31)*4;
    const float* rp = rowbase + (size_t)r*CONV_DIM + D_INNER;
    *(float4*)&Bt[r][c4] = *(const float4*)(rp + c4);
    *(float4*)&Ct[r][c4] = *(const float4*)(rp + D_STATE + c4);
  }
  if (tid < 32) {
    float A_h = -expf(A_log[h]);
    float dtv = dtp[((size_t)(b*SEQ + t0 + tid))*16 + h];
    float lc = dtv * A_h;
    #pragma unroll
    for (int d=1; d<32; d<<=1) {
      float o = __shfl_up(lc, d, 32);
      if (tid >= d) lc += o;
    }
    float lc31 = __shfl(lc, 31, 32);
    s_dt[tid] = dtv;
    s_lc[tid] = lc;
    s_wend[tid] = expf(lc31 - lc) * dtv;
    scl[cid*LCH + tid] = expf(lc);
    if (tid == 31) lcend[cid] = lc;
  }
  __syncthreads();

  // G phase: 2x2 per thread; M = mask*exp*dt*(C.B^T)
  {
    const int i0 = (tid >> 4) * 2;
    const int j0 = (tid & 15) * 2;
    float g00=0.f,g01=0.f,g10=0.f,g11=0.f;
    #pragma unroll 4
    for (int n=0;n<D_STATE;n++){
      float c0 = Ct[i0][n],  c1 = Ct[i0+1][n];
      float b0 = Bt[j0][n],  b1 = Bt[j0+1][n];
      g00 += c0*b0; g01 += c0*b1; g10 += c1*b0; g11 += c1*b1;
    }
    float li0 = s_lc[i0], li1 = s_lc[i0+1];
    float lj0 = s_lc[j0], lj1 = s_lc[j0+1];
    float d0 = s_dt[j0],  d1 = s_dt[j0+1];
    Mm[i0  ][j0  ] = (j0   <= i0  ) ? g00*expf(li0-lj0)*d0 : 0.f;
    Mm[i0  ][j0+1] = (j0+1 <= i0  ) ? g01*expf(li0-lj1)*d1 : 0.f;
    Mm[i0+1][j0  ] = (j0   <= i0+1) ? g10*expf(li1-lj0)*d0 : 0.f;
    Mm[i0+1][j0+1] = (j0+1 <= i0+1) ? g11*expf(li1-lj1)*d1 : 0.f;
  }
  __syncthreads();

  const int i0 = (tid >> 4) * 2;
  const int p0 = (tid & 15) * 4;
  // Y phase: y = M@X + D*x   (2 rows x 4 cols per thread)
  {
    const float dsk = D_skip[h];
    float a0[4], a1[4];
    #pragma unroll
    for (int q=0;q<4;q++){ a0[q] = dsk*Xt[i0][p0+q]; a1[q] = dsk*Xt[i0+1][p0+q]; }
    #pragma unroll 4
    for (int j=0;j<LCH;j++){
      float m0 = Mm[i0][j], m1 = Mm[i0+1][j];
      float x0=Xt[j][p0], x1=Xt[j][p0+1], x2=Xt[j][p0+2], x3=Xt[j][p0+3];
      a0[0]+=m0*x0; a0[1]+=m0*x1; a0[2]+=m0*x2; a0[3]+=m0*x3;
      a1[0]+=m1*x0; a1[1]+=m1*x1; a1[2]+=m1*x2; a1[3]+=m1*x3;
    }
    float* yr0 = y + ((size_t)(b*SEQ + t0 + i0))*D_INNER + h*HEADDIM + p0;
    float* yr1 = yr0 + D_INNER;
    *(float4*)yr0 = (float4){a0[0],a0[1],a0[2],a0[3]};
    *(float4*)yr1 = (float4){a1[0],a1[1],a1[2],a1[3]};
  }
  // S phase: S[n][p] = sum_j (wend_j*X[j][p]) * B[j][n]   (8n x 4p per thread)
  {
    const int n0 = (tid >> 4) * 8;
    float acc[8][4];
    #pragma unroll
    for (int nn=0;nn<8;nn++)
      #pragma unroll
      for (int q=0;q<4;q++) acc[nn][q]=0.f;
    #pragma unroll 2
    for (int j=0;j<LCH;j++){
      float w = s_wend[j];
      float x0=Xt[j][p0]*w, x1=Xt[j][p0+1]*w, x2=Xt[j][p0+2]*w, x3=Xt[j][p0+3]*w;
      #pragma unroll
      for (int nn=0;nn<8;nn++){
        float bb = Bt[j][n0+nn];
        acc[nn][0]+=bb*x0; acc[nn][1]+=bb*x1; acc[nn][2]+=bb*x2; acc[nn][3]+=bb*x3;
      }
    }
    __hip_bfloat16* Sout = Sbuf + (size_t)cid*(D_STATE*HEADDIM);
    #pragma unroll
    for (int nn=0;nn<8;nn++){
      ushort4 sv;
      sv.x = bf16bits(acc[nn][0]); sv.y = bf16bits(acc[nn][1]);
      sv.z = bf16bits(acc[nn][2]); sv.w = bf16bits(acc[nn][3]);
      *(ushort4*)(Sout + (n0+nn)*HEADDIM + p0) = sv;
    }
  }
}

// Kernel B: serial inter-chunk recurrence, 128 blocks (bh x 4 slices), uint4.
__global__ __launch_bounds__(256)
void state_scan(__hip_bfloat16* __restrict__ Sbuf, const float* __restrict__ lcend)
{
  const int bh = blockIdx.x >> 2;
  const int sl = blockIdx.x & 3;
  const int tid = threadIdx.x;
  uint4* Sb4 = (uint4*)Sbuf;
  const int idx0 = bh*NCHUNK*1024 + sl*256 + tid;   // uint4 units

  float H[8];
  #pragma unroll
  for (int r=0;r<8;r++) H[r]=0.f;
  uint4 cur = Sb4[idx0];
  float lcv = lcend[bh*NCHUNK];
  for (int c=0;c<NCHUNK;c++){
    uint4 nxt; float lcn;
    if (c < NCHUNK-1) { nxt = Sb4[idx0 + (c+1)*1024]; lcn = lcend[bh*NCHUNK + c + 1]; }
    else              { nxt = make_uint4(0,0,0,0);    lcn = 0.f; }
    float e = expf(lcv);
    uint4 o;
    o.x = bfpack2(H[0],H[1]); o.y = bfpack2(H[2],H[3]);
    o.z = bfpack2(H[4],H[5]); o.w = bfpack2(H[6],H[7]);
    Sb4[idx0 + c*1024] = o;
    H[0]=e*H[0]+blo(cur.x); H[1]=e*H[1]+bhi(cur.x);
    H[2]=e*H[2]+blo(cur.y); H[3]=e*H[3]+bhi(cur.y);
    H[4]=e*H[4]+blo(cur.z); H[5]=e*H[5]+bhi(cur.z);
    H[6]=e*H[6]+blo(cur.w); H[7]=e*H[7]+bhi(cur.w);
    cur = nxt; lcv = lcn;
  }
}

// Kernel C: y += exp(lc_i) * C_i @ H_prev   (2 rows x 4 cols per thread)
__global__ __launch_bounds__(256)
void chunk_inter(const float* __restrict__ xbc, const __hip_bfloat16* __restrict__ Sbuf,
                 const float* __restrict__ scl, float* __restrict__ y)
{
  __shared__ float Ct[LCH][SP];
  __shared__ float Hs[D_STATE][XP];
  const int cid = blockIdx.x;
  const int c  = cid & (NCHUNK-1);
  const int bh = cid >> 6;
  const int h  = bh & 15;
  const int b  = bh >> 4;
  const int tid = threadIdx.x;
  const int t0 = c*LCH;
  const float* rowbase = xbc + ((size_t)(b*SEQ + t0))*CONV_DIM;
  #pragma unroll
  for (int u=0;u<4;u++){
    int q = tid*4+u;
    int r = q>>5, c4 = (q&31)*4;
    *(float4*)&Ct[r][c4] = *(const float4*)(rowbase + (size_t)r*CONV_DIM + D_INNER + D_STATE + c4);
  }
  const unsigned* Hin = (const unsigned*)(Sbuf + (size_t)cid*(D_STATE*HEADDIM));
  #pragma unroll
  for (int u=0;u<16;u++){
    int q = tid + 256*u;            // uint index: elems 2q,2q+1
    unsigned uv = Hin[q];
    int r = q >> 5, col = (q & 31)*2;
    *(float2*)&Hs[r][col] = (float2){blo(uv), bhi(uv)};
  }
  __syncthreads();
  const int i0 = (tid >> 4) * 2;
  const int p0 = (tid & 15) * 4;
  float a0[4]={0.f,0.f,0.f,0.f}, a1[4]={0.f,0.f,0.f,0.f};
  #pragma unroll 4
  for (int n=0;n<D_STATE;n++){
    float c0 = Ct[i0][n], c1 = Ct[i0+1][n];
    float4 hv = *(const float4*)&Hs[n][p0];
    a0[0]+=c0*hv.x; a0[1]+=c0*hv.y; a0[2]+=c0*hv.z; a0[3]+=c0*hv.w;
    a1[0]+=c1*hv.x; a1[1]+=c1*hv.y; a1[2]+=c1*hv.z; a1[3]+=c1*hv.w;
  }
  float s0 = scl[cid*LCH + i0], s1 = scl[cid*LCH + i0 + 1];
  float* yr0 = y + ((size_t)(b*SEQ + t0 + i0))*D_INNER + h*HEADDIM + p0;
  float* yr1 = yr0 + D_INNER;
  float4 v0 = *(float4*)yr0, v1 = *(float4*)yr1;
  v0.x+=s0*a0[0]; v0.y+=s0*a0[1]; v0.z+=s0*a0[2]; v0.w+=s0*a0[3];
  v1.x+=s1*a1[0]; v1.y+=s1*a1[1]; v1.z+=s1*a1[2]; v1.w+=s1*a1[3];
  *(float4*)yr0 = v0; *(float4*)yr1 = v1;
}

// -------- y*silu(z), RMSNorm(1024)*gnorm_w -> bf16 out -----------------------
__global__ __launch_bounds__(256)
void gate_rms(const float* __restrict__ zx, const float* __restrict__ gw,
              const float* __restrict__ yin, __hip_bfloat16* __restrict__ ybf)
{
  int tok = blockIdx.x;
  const float* z = zx + (size_t)tok*D_IN_PROJ;
  const float* yr = yin + (size_t)tok*D_INNER;
  __hip_bfloat16* yo = ybf + (size_t)tok*D_INNER;
  float g[4];
  float ss = 0.f;
  #pragma unroll
  for (int i=0;i<4;i++) {
    int c = i*256 + threadIdx.x;
    float zv = z[c];
    float gv = yr[c] * (zv * sigmoid_f(zv));
    g[i]=gv; ss += gv*gv;
  }
  #pragma unroll
  for (int m=32;m>=1;m>>=1) ss += __shfl_xor(ss, m, 64);
  __shared__ float red[4];
  int wv = threadIdx.x >> 6;
  if ((threadIdx.x & 63)==0) red[wv]=ss;
  __syncthreads();
  float tot = red[0]+red[1]+red[2]+red[3];
  float sc = rsqrtf(tot*(1.f/1024.f) + 1e-5f);
  #pragma unroll
  for (int i=0;i<4;i++) {
    int c = i*256 + threadIdx.x;
    yo[c] = __float2bfloat16(g[i]*sc*gw[c]);
  }
}

// ---------------- out = LayerNorm(a + b); optional bf16 copy -----------------
template<int WBF>
__global__ __launch_bounds__(256)
void add_ln(const float* __restrict__ a, const float* __restrict__ bres,
            const float* __restrict__ gg, const float* __restrict__ bb,
            float* __restrict__ out, __hip_bfloat16* __restrict__ outbf)
{
  int tok = blockIdx.x;
  size_t o = (size_t)tok*D_MODEL;
  int c0 = threadIdx.x, c1 = threadIdx.x + 256;
  float v0 = a[o+c0] + bres[o+c0];
  float v1 = a[o+c1] + bres[o+c1];
  float s = v0+v1, sq = v0*v0+v1*v1;
  #pragma unroll
  for (int m=32;m>=1;m>>=1){ s += __shfl_xor(s,m,64); sq += __shfl_xor(sq,m,64); }
  __shared__ float rs[4], rq[4];
  int wv = threadIdx.x>>6;
  if ((threadIdx.x&63)==0){ rs[wv]=s; rq[wv]=sq; }
  __syncthreads();
  float S = rs[0]+rs[1]+rs[2]+rs[3];
  float Q = rq[0]+rq[1]+rq[2]+rq[3];
  float mean = S*(1.f/512.f);
  float var  = Q*(1.f/512.f) - mean*mean;
  float inv  = rsqrtf(var + 1e-5f);
  float o0 = (v0-mean)*inv*gg[c0] + bb[c0];
  float o1 = (v1-mean)*inv*gg[c1] + bb[c1];
  out[o+c0] = o0;
  out[o+c1] = o1;
  if (WBF) { outbf[o+c0] = __float2bfloat16(o0); outbf[o+c1] = __float2bfloat16(o1); }
}

extern "C" void kernel_launch(void* const* d_in, const int* in_sizes, int n_in,
                              void* d_out, int out_size, void* d_ws, size_t ws_size,
                              hipStream_t stream)
{
  const float* tgt    = (const float*)d_in[0];
  const float* W_in   = (const float*)d_in[1];
  const float* conv_w = (const float*)d_in[2];
  const float* conv_b = (const float*)d_in[3];
  const float* dt_bias= (const float*)d_in[4];
  const float* A_log  = (const float*)d_in[5];
  const float* D_skip = (const float*)d_in[6];
  const float* gnorm_w= (const float*)d_in[7];
  const float* W_out  = (const float*)d_in[8];
  const float* n1_g   = (const float*)d_in[9];
  const float* n1_b   = (const float*)d_in[10];
  const float* ffn_w1 = (const float*)d_in[11];
  const float* ffn_b1 = (const float*)d_in[12];
  const float* ffn_w2 = (const float*)d_in[13];
  const float* ffn_b2 = (const float*)d_in[14];
  const float* n3_g   = (const float*)d_in[15];
  const float* n3_b   = (const float*)d_in[16];
  float* out = (float*)d_out;
  float* ws  = (float*)d_ws;

  float* zx   = ws;                                   // 9,502,720
  float* xbc  = zx  + (size_t)NTOK*D_IN_PROJ;         // 5,242,880
  float* dtp  = xbc + (size_t)NTOK*CONV_DIM;          // 65,536
  float* yb   = dtp + (size_t)NTOK*16;                // 4,194,304
  float* Sreg = yb  + (size_t)NTOK*D_INNER;           // 8,388,608 (Sbuf bf16)
  __hip_bfloat16* Sbuf = (__hip_bfloat16*)Sreg;
  float* lcend= Sreg + (size_t)NCID*(D_STATE*HEADDIM)/2;
  float* scl  = lcend + NCID;

  __hip_bfloat16* tgt_bf = (__hip_bfloat16*)yb;
  __hip_bfloat16* Wint   = (__hip_bfloat16*)Sreg;
  __hip_bfloat16* yb_bf  = (__hip_bfloat16*)xbc;
  __hip_bfloat16* tb_bf  = (__hip_bfloat16*)(xbc + 2097152);
  float* tb   = Sreg;
  float* tmp  = Sreg + 2097152;
  __hip_bfloat16* Woutt  = (__hip_bfloat16*)(Sreg + 4194304);
  __hip_bfloat16* W1t    = (__hip_bfloat16*)(Sreg + 4194304 + 262144);
  __hip_bfloat16* W2t    = (__hip_bfloat16*)(Sreg + 4194304 + 262144 + 524288);
  __hip_bfloat16* hmid_bf= (__hip_bfloat16*)zx;

  transpose_to_bf16<<<dim3(NPJ_PAD/32, D_MODEL/32), 256, 0, stream>>>(W_in, Wint, D_MODEL, D_IN_PROJ, NPJ_PAD);
  f32_to_bf16_k<<<(NTOK*D_MODEL)/1024, 256, 0, stream>>>(tgt, tgt_bf, NTOK*D_MODEL);
  gemm_bf16<0,float><<<dim3(NPJ_PAD/64, NTOK/128), 256, 0, stream>>>(
      tgt_bf, Wint, nullptr, zx, D_IN_PROJ, D_MODEL, D_IN_PROJ);
  conv_silu<<<dim3(CONV_DIM/256, SEQ/64, B_SZ), 256, 0, stream>>>(zx, conv_w, conv_b, xbc);
  dt_kernel<<<(NTOK*16)/256, 256, 0, stream>>>(zx, dt_bias, dtp);
  chunk_intra<<<NCID, 256, 0, stream>>>(xbc, dtp, A_log, D_skip, yb, Sbuf, lcend, scl);
  state_scan<<<B_SZ*NHEADS*4, 256, 0, stream>>>(Sbuf, lcend);
  chunk_inter<<<NCID, 256, 0, stream>>>(xbc, Sbuf, scl, yb);
  transpose_to_bf16<<<dim3(D_MODEL/32, D_INNER/32), 256, 0, stream>>>(W_out, Woutt, D_INNER, D_MODEL, D_MODEL);
  transpose_to_bf16<<<dim3(FF/32, D_MODEL/32), 256, 0, stream>>>(ffn_w1, W1t, D_MODEL, FF, FF);
  transpose_to_bf16<<<dim3(D_MODEL/32, FF/32), 256, 0, stream>>>(ffn_w2, W2t, FF, D_MODEL, D_MODEL);
  gate_rms<<<NTOK, 256, 0, stream>>>(zx, gnorm_w, yb, yb_bf);
  gemm_bf16<0,float><<<dim3(D_MODEL/64, NTOK/128), 256, 0, stream>>>(
      yb_bf, Woutt, nullptr, tmp, D_MODEL, D_INNER, D_MODEL);
  add_ln<1><<<NTOK, 256, 0, stream>>>(tmp, tgt, n1_g, n1_b, tb, tb_bf);
  gemm_bf16<2,__hip_bfloat16><<<dim3(FF/64, NTOK/128), 256, 0, stream>>>(
      tb_bf, W1t, ffn_b1, hmid_bf, FF, D_MODEL, FF);
  gemm_bf16<1,float><<<dim3(D_MODEL/64, NTOK/128), 256, 0, stream>>>(
      hmid_bf, W2t, ffn_b2, tmp, D_MODEL, FF, D_MODEL);
  add_ln<0><<<NTOK, 256, 0, stream>>>(tmp, tb, n3_g, n3_b, out, nullptr);
}

// Round 5
// 213.870 us; speedup vs baseline: 6.9187x; 1.1305x over previous
//
#include <hip/hip_runtime.h>
#include <hip/hip_bf16.h>
#include <cstddef>
#include <cstdint>

#define D_MODEL   512
#define FF        2048
#define D_STATE   128
#define D_INNER   1024
#define HEADDIM   64
#define NHEADS    16
#define CONV_DIM  1280
#define D_IN_PROJ 2320
#define NPJ_PAD   2368      // D_IN_PROJ padded to 64
#define B_SZ      2
#define SEQ       2048
#define NTOK      (B_SZ*SEQ)   // 4096
#define LCH       32
#define NCHUNK    (SEQ/LCH)    // 64
#define NCID      (B_SZ*NHEADS*NCHUNK)  // 2048

typedef __attribute__((ext_vector_type(8))) short short8;
typedef __attribute__((ext_vector_type(4))) float f32x4;

__device__ __forceinline__ float sigmoid_f(float x){ return 1.0f/(1.0f+expf(-x)); }
__device__ __forceinline__ float gelu_f(float x){ return 0.5f*x*(1.0f+erff(x*0.70710678118654752f)); }

__device__ __forceinline__ unsigned short bf16bits(float f){
  __hip_bfloat16 h = __float2bfloat16(f);
  return *reinterpret_cast<unsigned short*>(&h);
}
__device__ __forceinline__ float blo(unsigned u){ return __uint_as_float(u<<16); }
__device__ __forceinline__ float bhi(unsigned u){ return __uint_as_float(u & 0xffff0000u); }
__device__ __forceinline__ unsigned bfpack2(float a, float b){
  return (unsigned)bf16bits(a) | ((unsigned)bf16bits(b)<<16);
}

__device__ __forceinline__ void gload16(const void* g, void* l){
  __builtin_amdgcn_global_load_lds((const __attribute__((address_space(1))) void*)g,
                                   (__attribute__((address_space(3))) void*)l, 16, 0, 0);
}

// ============ bf16 MFMA GEMM: C(MxN) = A(MxK)bf16 @ Bt(N_pad x K)bf16^T ======
template<int EPI, typename OT>   // EPI 0: none, 1: +bias, 2: gelu(.+bias)
__global__ __launch_bounds__(256)
void gemm_bf16(const __hip_bfloat16* __restrict__ A, const __hip_bfloat16* __restrict__ Bt,
               const float* __restrict__ bias, OT* __restrict__ C,
               int N, int K, int ldc)
{
  __shared__ char AsRaw[128*128];
  __shared__ char BsRaw[64*128];

  const int t    = threadIdx.x;
  const int bm   = blockIdx.y * 128;
  const int bn   = blockIdx.x * 64;
  const int lane = t & 63;
  const int wid  = t >> 6;
  const int wr   = wid >> 1;
  const int wc   = wid & 1;
  const int lrow = lane & 15;
  const int lkb  = (lane >> 4) * 16;
  const int sw   = (lrow & 7) << 4;

  const int rA  = t >> 3;
  const int cbA = (t & 7) * 16;
  const int scb = cbA ^ ((rA & 7) << 4);
  const size_t strideA = (size_t)K * 2;
  const char* aSrc = (const char*)A  + (size_t)(bm + rA) * strideA + scb;
  const char* bSrc = (const char*)Bt + (size_t)(bn + rA) * strideA + scb;
  char* aDst = AsRaw + (t >> 6) * 1024;
  char* bDst = BsRaw + (t >> 6) * 1024;

  f32x4 acc[4][2];
  #pragma unroll
  for (int m=0;m<4;m++)
    #pragma unroll
    for (int n=0;n<2;n++) acc[m][n] = (f32x4){0.f,0.f,0.f,0.f};

  const char* ArP = AsRaw + (wr*64 + lrow) * 128;
  const char* BrP = BsRaw + (wc*32 + lrow) * 128;

  for (int k0 = 0; k0 < K; k0 += 64) {
    const size_t ko = (size_t)k0 * 2;
    gload16(aSrc + ko,               aDst);
    gload16(aSrc + ko + 32*strideA,  aDst + 4096);
    gload16(aSrc + ko + 64*strideA,  aDst + 8192);
    gload16(aSrc + ko + 96*strideA,  aDst + 12288);
    gload16(bSrc + ko,               bDst);
    gload16(bSrc + ko + 32*strideA,  bDst + 4096);
    __syncthreads();
    #pragma unroll
    for (int kk = 0; kk < 2; ++kk) {
      const int kb = (kk*64 + lkb) ^ sw;
      short8 a0 = *(const short8*)(ArP + 0*2048 + kb);
      short8 a1 = *(const short8*)(ArP + 1*2048 + kb);
      short8 a2 = *(const short8*)(ArP + 2*2048 + kb);
      short8 a3 = *(const short8*)(ArP + 3*2048 + kb);
      short8 b0 = *(const short8*)(BrP + 0*2048 + kb);
      short8 b1 = *(const short8*)(BrP + 1*2048 + kb);
      acc[0][0] = __builtin_amdgcn_mfma_f32_16x16x32_bf16(a0, b0, acc[0][0], 0,0,0);
      acc[1][0] = __builtin_amdgcn_mfma_f32_16x16x32_bf16(a1, b0, acc[1][0], 0,0,0);
      acc[2][0] = __builtin_amdgcn_mfma_f32_16x16x32_bf16(a2, b0, acc[2][0], 0,0,0);
      acc[3][0] = __builtin_amdgcn_mfma_f32_16x16x32_bf16(a3, b0, acc[3][0], 0,0,0);
      acc[0][1] = __builtin_amdgcn_mfma_f32_16x16x32_bf16(a0, b1, acc[0][1], 0,0,0);
      acc[1][1] = __builtin_amdgcn_mfma_f32_16x16x32_bf16(a1, b1, acc[1][1], 0,0,0);
      acc[2][1] = __builtin_amdgcn_mfma_f32_16x16x32_bf16(a2, b1, acc[2][1], 0,0,0);
      acc[3][1] = __builtin_amdgcn_mfma_f32_16x16x32_bf16(a3, b1, acc[3][1], 0,0,0);
    }
    __syncthreads();
  }

  const int orow0 = bm + wr*64 + (lane >> 4) * 4;
  const int ocol0 = bn + wc*32 + lrow;
  #pragma unroll
  for (int n=0;n<2;n++) {
    const int col = ocol0 + n*16;
    if (col >= N) continue;
    const float bv = (EPI>=1) ? bias[col] : 0.f;
    #pragma unroll
    for (int m=0;m<4;m++) {
      #pragma unroll
      for (int j=0;j<4;j++) {
        float v = acc[m][n][j] + bv;
        if (EPI==2) v = gelu_f(v);
        OT* cp = C + (size_t)(orow0 + m*16 + j)*ldc + col;
        if constexpr (sizeof(OT)==2) *cp = __float2bfloat16(v); else *cp = v;
      }
    }
  }
}

// ---- transpose fp32 [K][N] -> bf16 [Npad][K] --------------------------------
__global__ __launch_bounds__(256)
void transpose_to_bf16(const float* __restrict__ in, __hip_bfloat16* __restrict__ out,
                       int K, int N, int Npad)
{
  __shared__ float tbuf[32][33];
  const int bx = blockIdx.x * 32;
  const int by = blockIdx.y * 32;
  const int tx = threadIdx.x & 31, ty = threadIdx.x >> 5;
  #pragma unroll
  for (int u=0;u<4;u++){
    int k = by + ty + u*8;
    int n = bx + tx;
    tbuf[ty+u*8][tx] = (n < N) ? in[(size_t)k*N + n] : 0.f;
  }
  __syncthreads();
  #pragma unroll
  for (int u=0;u<4;u++){
    int n = bx + ty + u*8;
    int k = by + tx;
    if (n < Npad) out[(size_t)n*K + k] = __float2bfloat16(tbuf[tx][ty+u*8]);
  }
}

__global__ __launch_bounds__(256)
void f32_to_bf16_k(const float* __restrict__ in, __hip_bfloat16* __restrict__ out, int n)
{
  int i = (blockIdx.x*256 + threadIdx.x)*4;
  if (i < n) {
    float4 v = *(const float4*)(in + i);
    out[i+0]=__float2bfloat16(v.x); out[i+1]=__float2bfloat16(v.y);
    out[i+2]=__float2bfloat16(v.z); out[i+3]=__float2bfloat16(v.w);
  }
}

// ------- depthwise causal conv(4)+SiLU, sliding-window registers -------------
__global__ __launch_bounds__(256)
void conv_silu(const float* __restrict__ zx, const float* __restrict__ cw,
               const float* __restrict__ cb, float* __restrict__ xbc)
{
  const int c  = blockIdx.x*256 + threadIdx.x;     // 0..1279
  const int t0 = blockIdx.y*64;
  const int b  = blockIdx.z;
  const float w0=cw[c*4+0], w1=cw[c*4+1], w2=cw[c*4+2], w3=cw[c*4+3];
  const float cbv = cb[c];
  const float* base = zx + ((size_t)(b*SEQ + t0))*D_IN_PROJ + D_INNER + c;
  float* obase = xbc + ((size_t)(b*SEQ + t0))*CONV_DIM + c;
  float xm3, xm2, xm1;
  if (t0 == 0) { xm3 = 0.f; xm2 = 0.f; xm1 = 0.f; }
  else {
    xm3 = base[-3*(ptrdiff_t)D_IN_PROJ];
    xm2 = base[-2*(ptrdiff_t)D_IN_PROJ];
    xm1 = base[-1*(ptrdiff_t)D_IN_PROJ];
  }
  #pragma unroll 4
  for (int t=0; t<64; ++t) {
    float xc = base[(size_t)t*D_IN_PROJ];
    float acc = cbv + w0*xm3 + w1*xm2 + w2*xm1 + w3*xc;
    obase[(size_t)t*CONV_DIM] = acc * sigmoid_f(acc);
    xm3 = xm2; xm2 = xm1; xm1 = xc;
  }
}

// ---------------- dt = softplus(raw + bias) ----------------------------------
__global__ __launch_bounds__(256)
void dt_kernel(const float* __restrict__ zx, const float* __restrict__ dt_bias,
               float* __restrict__ dtp)
{
  int idx = blockIdx.x*256 + threadIdx.x;
  int tok = idx >> 4, hh = idx & 15;
  float x = zx[(size_t)tok*D_IN_PROJ + (D_INNER + CONV_DIM) + hh] + dt_bias[hh];
  float sp = (x > 20.f) ? x : log1pf(expf(x));
  dtp[idx] = sp;
}

// ============== chunked SSD scan — MFMA version ===============================
// Per chunk (1 block, 4 waves):
//   G = C@B^T (16 MFMA), M̃ = mask*exp*dt*G + dsk*I  (bf16 in LDS)
//   Y = M̃@X                (8 MFMA; X consumed as X^T)
//   S^T = X^T @ B̃^T (wend folded into B̃^T) (32 MFMA), stored [p][n] bf16.
// LDS strides: 272B rows (K=128 tiles, 2-way read pattern), 96B rows (K=32).
__global__ __launch_bounds__(256)
void chunk_intra(const float* __restrict__ xbc, const float* __restrict__ dtp,
                 const float* __restrict__ A_log, const float* __restrict__ D_skip,
                 float* __restrict__ y, __hip_bfloat16* __restrict__ Sbuf,
                 float* __restrict__ lcend, float* __restrict__ scl)
{
  __shared__ char sm[38912];
  __shared__ float s_dt[LCH], s_lc[LCH], s_wend[LCH];
  char* Cb  = sm;            // [32] rows x 272B   (8704)
  char* Bb  = sm + 8704;     // [32] x 272B        (8704)
  char* Btb = sm + 17408;    // [128] rows x 96B   (12288)  B̃^T[n][j]
  char* Xtb = sm + 29696;    // [64] rows x 96B    (6144)   X^T[p][j]
  char* Mb  = sm + 35840;    // [32] rows x 96B    (3072)   M̃[i][j]
  // S-bounce overlays Cb+Bb: [64] rows x 272B = 17408B

  const int cid = blockIdx.x;
  const int c  = cid & (NCHUNK-1);
  const int bh = cid >> 6;
  const int h  = bh & 15;
  const int b  = bh >> 4;
  const int tid = threadIdx.x;
  const int t0 = c*LCH;
  const float* rowbase = xbc + ((size_t)(b*SEQ + t0))*CONV_DIM;

  // dt log-cumsum (first 32 lanes of wave 0)
  if (tid < 32) {
    float A_h = -expf(A_log[h]);
    float dtv = dtp[((size_t)(b*SEQ + t0 + tid))*16 + h];
    float lc = dtv * A_h;
    #pragma unroll
    for (int d=1; d<32; d<<=1) {
      float o = __shfl_up(lc, d, 32);
      if (tid >= d) lc += o;
    }
    float lc31 = __shfl(lc, 31, 32);
    s_dt[tid] = dtv;
    s_lc[tid] = lc;
    s_wend[tid] = expf(lc31 - lc) * dtv;
    scl[cid*LCH + tid] = expf(lc);
    if (tid == 31) lcend[cid] = lc;
  }

  // stage C_b, B_b (row-major bf16), X^T
  #pragma unroll
  for (int u=0; u<4; ++u) {
    int q = tid*4+u;
    int r = q>>5, c4 = (q&31)*4;
    const float* rp = rowbase + (size_t)r*CONV_DIM + D_INNER;
    float4 bv = *(const float4*)(rp + c4);
    float4 cv = *(const float4*)(rp + D_STATE + c4);
    *(uint2*)(Bb + r*272 + c4*2) = (uint2){bfpack2(bv.x,bv.y), bfpack2(bv.z,bv.w)};
    *(uint2*)(Cb + r*272 + c4*2) = (uint2){bfpack2(cv.x,cv.y), bfpack2(cv.z,cv.w)};
  }
  #pragma unroll
  for (int u=0; u<2; ++u) {
    int q = tid*2+u;
    int j = q>>4, p4 = (q&15)*4;
    float4 v = *(const float4*)(rowbase + (size_t)j*CONV_DIM + h*HEADDIM + p4);
    *(ushort*)(Xtb + ((p4+0)*48 + j)*2) = bf16bits(v.x);
    *(ushort*)(Xtb + ((p4+1)*48 + j)*2) = bf16bits(v.y);
    *(ushort*)(Xtb + ((p4+2)*48 + j)*2) = bf16bits(v.z);
    *(ushort*)(Xtb + ((p4+3)*48 + j)*2) = bf16bits(v.w);
  }
  __syncthreads();   // wend + C_b/B_b/Xt ready

  // stage B̃^T[n][j] = wend_j * B[j][n]  (re-read global, L2-hot)
  #pragma unroll
  for (int u=0; u<4; ++u) {
    int q = tid*4+u;
    int j = q>>5, n4 = (q&31)*4;
    const float w = s_wend[j];
    const float* rp = rowbase + (size_t)j*CONV_DIM + D_INNER;
    float4 v = *(const float4*)(rp + n4);
    *(ushort*)(Btb + ((n4+0)*48 + j)*2) = bf16bits(v.x*w);
    *(ushort*)(Btb + ((n4+1)*48 + j)*2) = bf16bits(v.y*w);
    *(ushort*)(Btb + ((n4+2)*48 + j)*2) = bf16bits(v.z*w);
    *(ushort*)(Btb + ((n4+3)*48 + j)*2) = bf16bits(v.w*w);
  }

  const int lane = tid & 63;
  const int w    = tid >> 6;
  const int lrow = lane & 15;
  const int lkb  = (lane >> 4) * 16;   // byte k-offset
  // ---- G phase: wave w -> quadrant (wi, wj) ----
  {
    const int wi = w >> 1, wj = w & 1;
    f32x4 g = (f32x4){0.f,0.f,0.f,0.f};
    const char* Ar = Cb + (wi*16 + lrow)*272 + lkb;
    const char* Br = Bb + (wj*16 + lrow)*272 + lkb;
    #pragma unroll
    for (int ks=0; ks<4; ks++){
      short8 a  = *(const short8*)(Ar + ks*64);
      short8 bb = *(const short8*)(Br + ks*64);
      g = __builtin_amdgcn_mfma_f32_16x16x32_bf16(a, bb, g, 0,0,0);
    }
    const int j = wj*16 + lrow;
    const float lcj = s_lc[j], dtj = s_dt[j];
    const float dsk = D_skip[h];
    const int i0 = wi*16 + (lane>>4)*4;
    #pragma unroll
    for (int r=0;r<4;r++){
      int i = i0 + r;
      float m = 0.f;
      if (j <= i) { m = g[r]*expf(s_lc[i]-lcj)*dtj; if (j==i) m += dsk; }
      *(ushort*)(Mb + (i*48 + j)*2) = bf16bits(m);
    }
  }
  __syncthreads();   // M̃ ready

  // ---- Y phase: wave w -> i-tile w>>1, p-tiles (w&1)*2..+1 ----
  {
    const int it = w >> 1;
    const int pb = (w & 1)*2;
    short8 am = *(const short8*)(Mb + (it*16+lrow)*96 + lkb);
    float* ybase = y + ((size_t)(b*SEQ+t0))*D_INNER + h*HEADDIM;
    #pragma unroll
    for (int pi=0; pi<2; pi++){
      short8 xv = *(const short8*)(Xtb + ((pb+pi)*16+lrow)*96 + lkb);
      f32x4 ya = __builtin_amdgcn_mfma_f32_16x16x32_bf16(am, xv, (f32x4){0.f,0.f,0.f,0.f}, 0,0,0);
      #pragma unroll
      for (int r=0;r<4;r++){
        int i = it*16 + (lane>>4)*4 + r;
        ybase[(size_t)i*D_INNER + (pb+pi)*16 + lrow] = ya[r];
      }
    }
  }

  // ---- S phase: S^T[p][n]; wave w -> p-tile w, n-tiles 0..7 ----
  f32x4 sacc[8];
  {
    short8 ax = *(const short8*)(Xtb + (w*16+lrow)*96 + lkb);
    #pragma unroll
    for (int nt=0;nt<8;nt++){
      short8 bv = *(const short8*)(Btb + (nt*16+lrow)*96 + lkb);
      sacc[nt] = __builtin_amdgcn_mfma_f32_16x16x32_bf16(ax, bv, (f32x4){0.f,0.f,0.f,0.f}, 0,0,0);
    }
  }
  __syncthreads();   // all reads of Cb/Bb region done -> safe to overlay
  {
    const int p0b = w*16 + (lane>>4)*4;
    #pragma unroll
    for (int nt=0;nt<8;nt++){
      int n = nt*16 + lrow;
      #pragma unroll
      for (int r=0;r<4;r++)
        *(ushort*)(sm + (p0b+r)*272 + n*2) = bf16bits(sacc[nt][r]);
    }
  }
  __syncthreads();
  __hip_bfloat16* Sout = Sbuf + (size_t)cid*(D_STATE*HEADDIM);
  #pragma unroll
  for (int u=0;u<4;u++){
    int q = tid*4+u, row = q>>4, c8 = (q&15)*8;
    *(uint4*)(Sout + row*128 + c8) = *(const uint4*)(sm + row*272 + c8*2);
  }
}

// Kernel B: serial inter-chunk recurrence, 128 blocks (bh x 4 slices), uint4.
// Layout-agnostic (elementwise across chunks at fixed intra-chunk index).
__global__ __launch_bounds__(256)
void state_scan(__hip_bfloat16* __restrict__ Sbuf, const float* __restrict__ lcend)
{
  const int bh = blockIdx.x >> 2;
  const int sl = blockIdx.x & 3;
  const int tid = threadIdx.x;
  uint4* Sb4 = (uint4*)Sbuf;
  const int idx0 = bh*NCHUNK*1024 + sl*256 + tid;   // uint4 units

  float H[8];
  #pragma unroll
  for (int r=0;r<8;r++) H[r]=0.f;
  uint4 cur = Sb4[idx0];
  float lcv = lcend[bh*NCHUNK];
  for (int c=0;c<NCHUNK;c++){
    uint4 nxt; float lcn;
    if (c < NCHUNK-1) { nxt = Sb4[idx0 + (c+1)*1024]; lcn = lcend[bh*NCHUNK + c + 1]; }
    else              { nxt = make_uint4(0,0,0,0);    lcn = 0.f; }
    float e = expf(lcv);
    uint4 o;
    o.x = bfpack2(H[0],H[1]); o.y = bfpack2(H[2],H[3]);
    o.z = bfpack2(H[4],H[5]); o.w = bfpack2(H[6],H[7]);
    Sb4[idx0 + c*1024] = o;
    H[0]=e*H[0]+blo(cur.x); H[1]=e*H[1]+bhi(cur.x);
    H[2]=e*H[2]+blo(cur.y); H[3]=e*H[3]+bhi(cur.y);
    H[4]=e*H[4]+blo(cur.z); H[5]=e*H[5]+bhi(cur.z);
    H[6]=e*H[6]+blo(cur.w); H[7]=e*H[7]+bhi(cur.w);
    cur = nxt; lcv = lcn;
  }
}

// Kernel C (MFMA): y += scl_i * C_i @ H_prev.  H stored as H^T[p][n] (=S^T).
__global__ __launch_bounds__(256)
void chunk_inter(const float* __restrict__ xbc, const __hip_bfloat16* __restrict__ Sbuf,
                 const float* __restrict__ scl, float* __restrict__ y)
{
  __shared__ char sm2[8704 + 17408];  // Cb [32]x272B, Ht [64]x272B
  __shared__ float s_scl[LCH];
  char* Cb = sm2;
  char* Ht = sm2 + 8704;
  const int cid = blockIdx.x;
  const int c  = cid & (NCHUNK-1);
  const int bh = cid >> 6;
  const int h  = bh & 15;
  const int b  = bh >> 4;
  const int tid = threadIdx.x;
  const int t0 = c*LCH;
  const float* rowbase = xbc + ((size_t)(b*SEQ + t0))*CONV_DIM;

  #pragma unroll
  for (int u=0;u<4;u++){
    int q = tid*4+u;
    int r = q>>5, c4 = (q&31)*4;
    float4 wv = *(const float4*)(rowbase + (size_t)r*CONV_DIM + D_INNER + D_STATE + c4);
    *(uint2*)(Cb + r*272 + c4*2) = (uint2){bfpack2(wv.x,wv.y), bfpack2(wv.z,wv.w)};
  }
  const uint4* Hin = (const uint4*)(Sbuf + (size_t)cid*(D_STATE*HEADDIM));
  #pragma unroll
  for (int u=0;u<4;u++){
    int q = tid*4+u, row = q>>4, c8 = (q&15)*8;
    *(uint4*)(Ht + row*272 + c8*2) = Hin[q];
  }
  if (tid < 32) s_scl[tid] = scl[cid*LCH + tid];
  __syncthreads();

  const int lane = tid & 63;
  const int w    = tid >> 6;
  const int lrow = lane & 15;
  const int lkb  = (lane >> 4) * 16;
  const int it   = w >> 1;
  const int pb   = (w & 1)*2;
  f32x4 acc[2];
  acc[0] = (f32x4){0.f,0.f,0.f,0.f};
  acc[1] = (f32x4){0.f,0.f,0.f,0.f};
  const char* Ar = Cb + (it*16+lrow)*272 + lkb;
  const char* H0 = Ht + ((pb+0)*16+lrow)*272 + lkb;
  const char* H1 = Ht + ((pb+1)*16+lrow)*272 + lkb;
  #pragma unroll
  for (int ks=0; ks<4; ks++){
    short8 a  = *(const short8*)(Ar + ks*64);
    short8 h0 = *(const short8*)(H0 + ks*64);
    short8 h1 = *(const short8*)(H1 + ks*64);
    acc[0] = __builtin_amdgcn_mfma_f32_16x16x32_bf16(a, h0, acc[0], 0,0,0);
    acc[1] = __builtin_amdgcn_mfma_f32_16x16x32_bf16(a, h1, acc[1], 0,0,0);
  }
  float* ybase = y + ((size_t)(b*SEQ+t0))*D_INNER + h*HEADDIM;
  #pragma unroll
  for (int pi=0; pi<2; pi++){
    #pragma unroll
    for (int r=0;r<4;r++){
      int i = it*16 + (lane>>4)*4 + r;
      float* yp = ybase + (size_t)i*D_INNER + (pb+pi)*16 + lrow;
      *yp += s_scl[i]*acc[pi][r];
    }
  }
}

// -------- y*silu(z), RMSNorm(1024)*gnorm_w -> bf16 out -----------------------
__global__ __launch_bounds__(256)
void gate_rms(const float* __restrict__ zx, const float* __restrict__ gw,
              const float* __restrict__ yin, __hip_bfloat16* __restrict__ ybf)
{
  int tok = blockIdx.x;
  const float* z = zx + (size_t)tok*D_IN_PROJ;
  const float* yr = yin + (size_t)tok*D_INNER;
  __hip_bfloat16* yo = ybf + (size_t)tok*D_INNER;
  float g[4];
  float ss = 0.f;
  #pragma unroll
  for (int i=0;i<4;i++) {
    int c = i*256 + threadIdx.x;
    float zv = z[c];
    float gv = yr[c] * (zv * sigmoid_f(zv));
    g[i]=gv; ss += gv*gv;
  }
  #pragma unroll
  for (int m=32;m>=1;m>>=1) ss += __shfl_xor(ss, m, 64);
  __shared__ float red[4];
  int wv = threadIdx.x >> 6;
  if ((threadIdx.x & 63)==0) red[wv]=ss;
  __syncthreads();
  float tot = red[0]+red[1]+red[2]+red[3];
  float sc = rsqrtf(tot*(1.f/1024.f) + 1e-5f);
  #pragma unroll
  for (int i=0;i<4;i++) {
    int c = i*256 + threadIdx.x;
    yo[c] = __float2bfloat16(g[i]*sc*gw[c]);
  }
}

// ---------------- out = LayerNorm(a + b); optional bf16 copy -----------------
template<int WBF>
__global__ __launch_bounds__(256)
void add_ln(const float* __restrict__ a, const float* __restrict__ bres,
            const float* __restrict__ gg, const float* __restrict__ bb,
            float* __restrict__ out, __hip_bfloat16* __restrict__ outbf)
{
  int tok = blockIdx.x;
  size_t o = (size_t)tok*D_MODEL;
  int c0 = threadIdx.x, c1 = threadIdx.x + 256;
  float v0 = a[o+c0] + bres[o+c0];
  float v1 = a[o+c1] + bres[o+c1];
  float s = v0+v1, sq = v0*v0+v1*v1;
  #pragma unroll
  for (int m=32;m>=1;m>>=1){ s += __shfl_xor(s,m,64); sq += __shfl_xor(sq,m,64); }
  __shared__ float rs[4], rq[4];
  int wv = threadIdx.x>>6;
  if ((threadIdx.x&63)==0){ rs[wv]=s; rq[wv]=sq; }
  __syncthreads();
  float S = rs[0]+rs[1]+rs[2]+rs[3];
  float Q = rq[0]+rq[1]+rq[2]+rq[3];
  float mean = S*(1.f/512.f);
  float var  = Q*(1.f/512.f) - mean*mean;
  float inv  = rsqrtf(var + 1e-5f);
  float o0 = (v0-mean)*inv*gg[c0] + bb[c0];
  float o1 = (v1-mean)*inv*gg[c1] + bb[c1];
  out[o+c0] = o0;
  out[o+c1] = o1;
  if (WBF) { outbf[o+c0] = __float2bfloat16(o0); outbf[o+c1] = __float2bfloat16(o1); }
}

extern "C" void kernel_launch(void* const* d_in, const int* in_sizes, int n_in,
                              void* d_out, int out_size, void* d_ws, size_t ws_size,
                              hipStream_t stream)
{
  const float* tgt    = (const float*)d_in[0];
  const float* W_in   = (const float*)d_in[1];
  const float* conv_w = (const float*)d_in[2];
  const float* conv_b = (const float*)d_in[3];
  const float* dt_bias= (const float*)d_in[4];
  const float* A_log  = (const float*)d_in[5];
  const float* D_skip = (const float*)d_in[6];
  const float* gnorm_w= (const float*)d_in[7];
  const float* W_out  = (const float*)d_in[8];
  const float* n1_g   = (const float*)d_in[9];
  const float* n1_b   = (const float*)d_in[10];
  const float* ffn_w1 = (const float*)d_in[11];
  const float* ffn_b1 = (const float*)d_in[12];
  const float* ffn_w2 = (const float*)d_in[13];
  const float* ffn_b2 = (const float*)d_in[14];
  const float* n3_g   = (const float*)d_in[15];
  const float* n3_b   = (const float*)d_in[16];
  float* out = (float*)d_out;
  float* ws  = (float*)d_ws;

  float* zx   = ws;                                   // 9,502,720
  float* xbc  = zx  + (size_t)NTOK*D_IN_PROJ;         // 5,242,880
  float* dtp  = xbc + (size_t)NTOK*CONV_DIM;          // 65,536
  float* yb   = dtp + (size_t)NTOK*16;                // 4,194,304
  float* Sreg = yb  + (size_t)NTOK*D_INNER;           // 8,388,608 (Sbuf bf16)
  __hip_bfloat16* Sbuf = (__hip_bfloat16*)Sreg;
  float* lcend= Sreg + (size_t)NCID*(D_STATE*HEADDIM)/2;
  float* scl  = lcend + NCID;

  __hip_bfloat16* tgt_bf = (__hip_bfloat16*)yb;
  __hip_bfloat16* Wint   = (__hip_bfloat16*)Sreg;
  __hip_bfloat16* yb_bf  = (__hip_bfloat16*)xbc;
  __hip_bfloat16* tb_bf  = (__hip_bfloat16*)(xbc + 2097152);
  float* tb   = Sreg;
  float* tmp  = Sreg + 2097152;
  __hip_bfloat16* Woutt  = (__hip_bfloat16*)(Sreg + 4194304);
  __hip_bfloat16* W1t    = (__hip_bfloat16*)(Sreg + 4194304 + 262144);
  __hip_bfloat16* W2t    = (__hip_bfloat16*)(Sreg + 4194304 + 262144 + 524288);
  __hip_bfloat16* hmid_bf= (__hip_bfloat16*)zx;

  transpose_to_bf16<<<dim3(NPJ_PAD/32, D_MODEL/32), 256, 0, stream>>>(W_in, Wint, D_MODEL, D_IN_PROJ, NPJ_PAD);
  f32_to_bf16_k<<<(NTOK*D_MODEL)/1024, 256, 0, stream>>>(tgt, tgt_bf, NTOK*D_MODEL);
  gemm_bf16<0,float><<<dim3(NPJ_PAD/64, NTOK/128), 256, 0, stream>>>(
      tgt_bf, Wint, nullptr, zx, D_IN_PROJ, D_MODEL, D_IN_PROJ);
  conv_silu<<<dim3(CONV_DIM/256, SEQ/64, B_SZ), 256, 0, stream>>>(zx, conv_w, conv_b, xbc);
  dt_kernel<<<(NTOK*16)/256, 256, 0, stream>>>(zx, dt_bias, dtp);
  chunk_intra<<<NCID, 256, 0, stream>>>(xbc, dtp, A_log, D_skip, yb, Sbuf, lcend, scl);
  state_scan<<<B_SZ*NHEADS*4, 256, 0, stream>>>(Sbuf, lcend);
  chunk_inter<<<NCID, 256, 0, stream>>>(xbc, Sbuf, scl, yb);
  transpose_to_bf16<<<dim3(D_MODEL/32, D_INNER/32), 256, 0, stream>>>(W_out, Woutt, D_INNER, D_MODEL, D_MODEL);
  transpose_to_bf16<<<dim3(FF/32, D_MODEL/32), 256, 0, stream>>>(ffn_w1, W1t, D_MODEL, FF, FF);
  transpose_to_bf16<<<dim3(D_MODEL/32, FF/32), 256, 0, stream>>>(ffn_w2, W2t, FF, D_MODEL, D_MODEL);
  gate_rms<<<NTOK, 256, 0, stream>>>(zx, gnorm_w, yb, yb_bf);
  gemm_bf16<0,float><<<dim3(D_MODEL/64, NTOK/128), 256, 0, stream>>>(
      yb_bf, Woutt, nullptr, tmp, D_MODEL, D_INNER, D_MODEL);
  add_ln<1><<<NTOK, 256, 0, stream>>>(tmp, tgt, n1_g, n1_b, tb, tb_bf);
  gemm_bf16<2,__hip_bfloat16><<<dim3(FF/64, NTOK/128), 256, 0, stream>>>(
      tb_bf, W1t, ffn_b1, hmid_bf, FF, D_MODEL, FF);
  gemm_bf16<1,float><<<dim3(D_MODEL/64, NTOK/128), 256, 0, stream>>>(
      hmid_bf, W2t, ffn_b2, tmp, D_MODEL, FF, D_MODEL);
  add_ln<0><<<NTOK, 256, 0, stream>>>(tmp, tb, n3_g, n3_b, out, nullptr);
}

// Round 6
// 211.963 us; speedup vs baseline: 6.9809x; 1.0090x over previous
//
#include <hip/hip_runtime.h>
#include <hip/hip_bf16.h>
#include <cstddef>
#include <cstdint>

#define D_MODEL   512
#define FF        2048
#define D_STATE   128
#define D_INNER   1024
#define HEADDIM   64
#define NHEADS    16
#define CONV_DIM  1280
#define D_IN_PROJ 2320
#define NPJ_PAD   2432      // D_IN_PROJ padded to 128
#define B_SZ      2
#define SEQ       2048
#define NTOK      (B_SZ*SEQ)   // 4096
#define LCH       32
#define NCHUNK    (SEQ/LCH)    // 64
#define NCID      (B_SZ*NHEADS*NCHUNK)  // 2048

typedef __attribute__((ext_vector_type(8))) short short8;
typedef __attribute__((ext_vector_type(4))) float f32x4;

__device__ __forceinline__ float sigmoid_f(float x){ return 1.0f/(1.0f+expf(-x)); }
__device__ __forceinline__ float gelu_f(float x){ return 0.5f*x*(1.0f+erff(x*0.70710678118654752f)); }

__device__ __forceinline__ unsigned short bf16bits(float f){
  __hip_bfloat16 h = __float2bfloat16(f);
  return *reinterpret_cast<unsigned short*>(&h);
}
__device__ __forceinline__ float bf2f(unsigned short u){ return __uint_as_float(((unsigned)u)<<16); }
__device__ __forceinline__ float blo(unsigned u){ return __uint_as_float(u<<16); }
__device__ __forceinline__ float bhi(unsigned u){ return __uint_as_float(u & 0xffff0000u); }
__device__ __forceinline__ unsigned bfpack2(float a, float b){
  return (unsigned)bf16bits(a) | ((unsigned)bf16bits(b)<<16);
}

__device__ __forceinline__ void gload16(const void* g, void* l){
  __builtin_amdgcn_global_load_lds((const __attribute__((address_space(1))) void*)g,
                                   (__attribute__((address_space(3))) void*)l, 16, 0, 0);
}

union U4S8 { uint4 v; unsigned short s[8]; };

// ============ m97-structure GEMM: BM=128,BN=128,BK=64, 4 waves of 64x64 ======
template<int EPI, typename OT>   // EPI 0: none, 1: +bias, 2: gelu(.+bias)
__global__ __launch_bounds__(256)
void gemm128(const __hip_bfloat16* __restrict__ A, const __hip_bfloat16* __restrict__ Bt,
             const float* __restrict__ bias, OT* __restrict__ C,
             int N, int K, int ldc)
{
  __shared__ char AsRaw[128*128];
  __shared__ char BsRaw[128*128];

  const int t    = threadIdx.x;
  const int bm   = blockIdx.y * 128;
  const int bn   = blockIdx.x * 128;
  const int lane = t & 63;
  const int wid  = t >> 6;
  const int wr   = wid >> 1;
  const int wc   = wid & 1;
  const int lrow = lane & 15;
  const int lkb  = (lane >> 4) * 16;
  const int sw   = (lrow & 7) << 4;

  const int rA  = t >> 3;
  const int cbA = (t & 7) * 16;
  const int scb = cbA ^ ((rA & 7) << 4);
  const size_t strideA = (size_t)K * 2;
  const char* aSrc = (const char*)A  + (size_t)(bm + rA) * strideA + scb;
  const char* bSrc = (const char*)Bt + (size_t)(bn + rA) * strideA + scb;
  char* aDst = AsRaw + wid * 1024;
  char* bDst = BsRaw + wid * 1024;

  f32x4 acc[4][4];
  #pragma unroll
  for (int m=0;m<4;m++)
    #pragma unroll
    for (int n=0;n<4;n++) acc[m][n] = (f32x4){0.f,0.f,0.f,0.f};

  const char* ArP = AsRaw + (wr*64 + lrow) * 128;
  const char* BrP = BsRaw + (wc*64 + lrow) * 128;

  for (int k0 = 0; k0 < K; k0 += 64) {
    const size_t ko = (size_t)k0 * 2;
    gload16(aSrc + ko,               aDst);
    gload16(aSrc + ko + 32*strideA,  aDst + 4096);
    gload16(aSrc + ko + 64*strideA,  aDst + 8192);
    gload16(aSrc + ko + 96*strideA,  aDst + 12288);
    gload16(bSrc + ko,               bDst);
    gload16(bSrc + ko + 32*strideA,  bDst + 4096);
    gload16(bSrc + ko + 64*strideA,  bDst + 8192);
    gload16(bSrc + ko + 96*strideA,  bDst + 12288);
    __syncthreads();
    #pragma unroll
    for (int kk = 0; kk < 2; ++kk) {
      const int kb = (kk*64 + lkb) ^ sw;
      short8 a0 = *(const short8*)(ArP + 0*2048 + kb);
      short8 a1 = *(const short8*)(ArP + 1*2048 + kb);
      short8 a2 = *(const short8*)(ArP + 2*2048 + kb);
      short8 a3 = *(const short8*)(ArP + 3*2048 + kb);
      short8 b0 = *(const short8*)(BrP + 0*2048 + kb);
      short8 b1 = *(const short8*)(BrP + 1*2048 + kb);
      short8 b2 = *(const short8*)(BrP + 2*2048 + kb);
      short8 b3 = *(const short8*)(BrP + 3*2048 + kb);
      #pragma unroll
      for (int m=0;m<4;m++){
        short8 am = (m==0)?a0:(m==1)?a1:(m==2)?a2:a3;
        acc[m][0] = __builtin_amdgcn_mfma_f32_16x16x32_bf16(am, b0, acc[m][0], 0,0,0);
        acc[m][1] = __builtin_amdgcn_mfma_f32_16x16x32_bf16(am, b1, acc[m][1], 0,0,0);
        acc[m][2] = __builtin_amdgcn_mfma_f32_16x16x32_bf16(am, b2, acc[m][2], 0,0,0);
        acc[m][3] = __builtin_amdgcn_mfma_f32_16x16x32_bf16(am, b3, acc[m][3], 0,0,0);
      }
    }
    __syncthreads();
  }

  const int orow0 = bm + wr*64 + (lane >> 4) * 4;
  const int ocol0 = bn + wc*64 + lrow;
  #pragma unroll
  for (int n=0;n<4;n++) {
    const int col = ocol0 + n*16;
    if (col >= N) continue;
    const float bv = (EPI>=1) ? bias[col] : 0.f;
    #pragma unroll
    for (int m=0;m<4;m++) {
      #pragma unroll
      for (int j=0;j<4;j++) {
        float v = acc[m][n][j] + bv;
        if (EPI==2) v = gelu_f(v);
        OT* cp = C + (size_t)(orow0 + m*16 + j)*ldc + col;
        if constexpr (sizeof(OT)==2) *cp = __float2bfloat16(v); else *cp = v;
      }
    }
  }
}

// ============ 128x64 GEMM (for N=512 shapes: more blocks -> better occupancy) =
template<int EPI, typename OT>
__global__ __launch_bounds__(256)
void gemm_bf16(const __hip_bfloat16* __restrict__ A, const __hip_bfloat16* __restrict__ Bt,
               const float* __restrict__ bias, OT* __restrict__ C,
               int N, int K, int ldc)
{
  __shared__ char AsRaw[128*128];
  __shared__ char BsRaw[64*128];

  const int t    = threadIdx.x;
  const int bm   = blockIdx.y * 128;
  const int bn   = blockIdx.x * 64;
  const int lane = t & 63;
  const int wid  = t >> 6;
  const int wr   = wid >> 1;
  const int wc   = wid & 1;
  const int lrow = lane & 15;
  const int lkb  = (lane >> 4) * 16;
  const int sw   = (lrow & 7) << 4;

  const int rA  = t >> 3;
  const int cbA = (t & 7) * 16;
  const int scb = cbA ^ ((rA & 7) << 4);
  const size_t strideA = (size_t)K * 2;
  const char* aSrc = (const char*)A  + (size_t)(bm + rA) * strideA + scb;
  const char* bSrc = (const char*)Bt + (size_t)(bn + rA) * strideA + scb;
  char* aDst = AsRaw + wid * 1024;
  char* bDst = BsRaw + wid * 1024;

  f32x4 acc[4][2];
  #pragma unroll
  for (int m=0;m<4;m++)
    #pragma unroll
    for (int n=0;n<2;n++) acc[m][n] = (f32x4){0.f,0.f,0.f,0.f};

  const char* ArP = AsRaw + (wr*64 + lrow) * 128;
  const char* BrP = BsRaw + (wc*32 + lrow) * 128;

  for (int k0 = 0; k0 < K; k0 += 64) {
    const size_t ko = (size_t)k0 * 2;
    gload16(aSrc + ko,               aDst);
    gload16(aSrc + ko + 32*strideA,  aDst + 4096);
    gload16(aSrc + ko + 64*strideA,  aDst + 8192);
    gload16(aSrc + ko + 96*strideA,  aDst + 12288);
    gload16(bSrc + ko,               bDst);
    gload16(bSrc + ko + 32*strideA,  bDst + 4096);
    __syncthreads();
    #pragma unroll
    for (int kk = 0; kk < 2; ++kk) {
      const int kb = (kk*64 + lkb) ^ sw;
      short8 a0 = *(const short8*)(ArP + 0*2048 + kb);
      short8 a1 = *(const short8*)(ArP + 1*2048 + kb);
      short8 a2 = *(const short8*)(ArP + 2*2048 + kb);
      short8 a3 = *(const short8*)(ArP + 3*2048 + kb);
      short8 b0 = *(const short8*)(BrP + 0*2048 + kb);
      short8 b1 = *(const short8*)(BrP + 1*2048 + kb);
      acc[0][0] = __builtin_amdgcn_mfma_f32_16x16x32_bf16(a0, b0, acc[0][0], 0,0,0);
      acc[1][0] = __builtin_amdgcn_mfma_f32_16x16x32_bf16(a1, b0, acc[1][0], 0,0,0);
      acc[2][0] = __builtin_amdgcn_mfma_f32_16x16x32_bf16(a2, b0, acc[2][0], 0,0,0);
      acc[3][0] = __builtin_amdgcn_mfma_f32_16x16x32_bf16(a3, b0, acc[3][0], 0,0,0);
      acc[0][1] = __builtin_amdgcn_mfma_f32_16x16x32_bf16(a0, b1, acc[0][1], 0,0,0);
      acc[1][1] = __builtin_amdgcn_mfma_f32_16x16x32_bf16(a1, b1, acc[1][1], 0,0,0);
      acc[2][1] = __builtin_amdgcn_mfma_f32_16x16x32_bf16(a2, b1, acc[2][1], 0,0,0);
      acc[3][1] = __builtin_amdgcn_mfma_f32_16x16x32_bf16(a3, b1, acc[3][1], 0,0,0);
    }
    __syncthreads();
  }

  const int orow0 = bm + wr*64 + (lane >> 4) * 4;
  const int ocol0 = bn + wc*32 + lrow;
  #pragma unroll
  for (int n=0;n<2;n++) {
    const int col = ocol0 + n*16;
    if (col >= N) continue;
    const float bv = (EPI>=1) ? bias[col] : 0.f;
    #pragma unroll
    for (int m=0;m<4;m++) {
      #pragma unroll
      for (int j=0;j<4;j++) {
        float v = acc[m][n][j] + bv;
        if (EPI==2) v = gelu_f(v);
        OT* cp = C + (size_t)(orow0 + m*16 + j)*ldc + col;
        if constexpr (sizeof(OT)==2) *cp = __float2bfloat16(v); else *cp = v;
      }
    }
  }
}

// ---- transpose fp32 [K][N] -> bf16 [Npad][K] --------------------------------
__global__ __launch_bounds__(256)
void transpose_to_bf16(const float* __restrict__ in, __hip_bfloat16* __restrict__ out,
                       int K, int N, int Npad)
{
  __shared__ float tbuf[32][33];
  const int bx = blockIdx.x * 32;
  const int by = blockIdx.y * 32;
  const int tx = threadIdx.x & 31, ty = threadIdx.x >> 5;
  #pragma unroll
  for (int u=0;u<4;u++){
    int k = by + ty + u*8;
    int n = bx + tx;
    tbuf[ty+u*8][tx] = (n < N) ? in[(size_t)k*N + n] : 0.f;
  }
  __syncthreads();
  #pragma unroll
  for (int u=0;u<4;u++){
    int n = bx + ty + u*8;
    int k = by + tx;
    if (n < Npad) out[(size_t)n*K + k] = __float2bfloat16(tbuf[tx][ty+u*8]);
  }
}

__global__ __launch_bounds__(256)
void f32_to_bf16_k(const float* __restrict__ in, __hip_bfloat16* __restrict__ out, int n)
{
  int i = (blockIdx.x*256 + threadIdx.x)*4;
  if (i < n) {
    float4 v = *(const float4*)(in + i);
    out[i+0]=__float2bfloat16(v.x); out[i+1]=__float2bfloat16(v.y);
    out[i+2]=__float2bfloat16(v.z); out[i+3]=__float2bfloat16(v.w);
  }
}

// ------- depthwise causal conv(4)+SiLU -> bf16 xbc; block x==0 also does dt --
__global__ __launch_bounds__(256)
void conv_silu(const float* __restrict__ zx, const float* __restrict__ cw,
               const float* __restrict__ cb, __hip_bfloat16* __restrict__ xbc,
               const float* __restrict__ dt_bias, float* __restrict__ dtp)
{
  const int c  = blockIdx.x*256 + threadIdx.x;     // 0..1279
  const int t0 = blockIdx.y*64;
  const int b  = blockIdx.z;
  const float w0=cw[c*4+0], w1=cw[c*4+1], w2=cw[c*4+2], w3=cw[c*4+3];
  const float cbv = cb[c];
  const float* base = zx + ((size_t)(b*SEQ + t0))*D_IN_PROJ + D_INNER + c;
  __hip_bfloat16* obase = xbc + ((size_t)(b*SEQ + t0))*CONV_DIM + c;
  float xm3, xm2, xm1;
  if (t0 == 0) { xm3 = 0.f; xm2 = 0.f; xm1 = 0.f; }
  else {
    xm3 = base[-3*(ptrdiff_t)D_IN_PROJ];
    xm2 = base[-2*(ptrdiff_t)D_IN_PROJ];
    xm1 = base[-1*(ptrdiff_t)D_IN_PROJ];
  }
  #pragma unroll 4
  for (int t=0; t<64; ++t) {
    float xc = base[(size_t)t*D_IN_PROJ];
    float acc = cbv + w0*xm3 + w1*xm2 + w2*xm1 + w3*xc;
    obase[(size_t)t*CONV_DIM] = __float2bfloat16(acc * sigmoid_f(acc));
    xm3 = xm2; xm2 = xm1; xm1 = xc;
  }
  // fused dt: block x==0 covers 64 tokens x 16 heads
  if (blockIdx.x == 0) {
    #pragma unroll
    for (int it=0; it<4; ++it) {
      int idx = it*256 + threadIdx.x;
      int tloc = idx >> 4, hh = idx & 15;
      int tok = b*SEQ + t0 + tloc;
      float x = zx[(size_t)tok*D_IN_PROJ + (D_INNER + CONV_DIM) + hh] + dt_bias[hh];
      float sp = (x > 20.f) ? x : log1pf(expf(x));
      dtp[tok*16 + hh] = sp;
    }
  }
}

// ============== chunked SSD scan — MFMA version (bf16 xbc) ====================
__global__ __launch_bounds__(256)
void chunk_intra(const __hip_bfloat16* __restrict__ xbc, const float* __restrict__ dtp,
                 const float* __restrict__ A_log, const float* __restrict__ D_skip,
                 float* __restrict__ y, __hip_bfloat16* __restrict__ Sbuf,
                 float* __restrict__ lcend, float* __restrict__ scl)
{
  __shared__ char sm[38912];
  __shared__ float s_dt[LCH], s_lc[LCH], s_wend[LCH];
  char* Cb  = sm;            // [32] rows x 272B   (8704)
  char* Bb  = sm + 8704;     // [32] x 272B        (8704)
  char* Btb = sm + 17408;    // [128] rows x 96B   (12288)  B̃^T[n][j]
  char* Xtb = sm + 29696;    // [64] rows x 96B    (6144)   X^T[p][j]
  char* Mb  = sm + 35840;    // [32] rows x 96B    (3072)   M̃[i][j]

  const int cid = blockIdx.x;
  const int c  = cid & (NCHUNK-1);
  const int bh = cid >> 6;
  const int h  = bh & 15;
  const int b  = bh >> 4;
  const int tid = threadIdx.x;
  const int t0 = c*LCH;
  const __hip_bfloat16* rowbase = xbc + ((size_t)(b*SEQ + t0))*CONV_DIM;

  if (tid < 32) {
    float A_h = -expf(A_log[h]);
    float dtv = dtp[((size_t)(b*SEQ + t0 + tid))*16 + h];
    float lc = dtv * A_h;
    #pragma unroll
    for (int d=1; d<32; d<<=1) {
      float o = __shfl_up(lc, d, 32);
      if (tid >= d) lc += o;
    }
    float lc31 = __shfl(lc, 31, 32);
    s_dt[tid] = dtv;
    s_lc[tid] = lc;
    s_wend[tid] = expf(lc31 - lc) * dtv;
    scl[cid*LCH + tid] = expf(lc);
    if (tid == 31) lcend[cid] = lc;
  }

  // stage B_b, C_b: direct uint4 copies (bf16 global -> LDS rows 272B)
  #pragma unroll
  for (int u=0; u<2; ++u) {
    int q = tid + 256*u;
    int r = q >> 4, c8 = (q & 15)*8;
    const __hip_bfloat16* rp = rowbase + (size_t)r*CONV_DIM + D_INNER;
    *(uint4*)(Bb + r*272 + c8*2) = *(const uint4*)(rp + c8);
    *(uint4*)(Cb + r*272 + c8*2) = *(const uint4*)(rp + D_STATE + c8);
  }
  // stage X^T: thread tid -> row j=tid>>3, cols p0..p0+7
  {
    int j = tid >> 3, p0 = (tid & 7)*8;
    U4S8 xv; xv.v = *(const uint4*)(rowbase + (size_t)j*CONV_DIM + h*HEADDIM + p0);
    #pragma unroll
    for (int k=0;k<8;k++)
      *(unsigned short*)(Xtb + ((p0+k)*48 + j)*2) = xv.s[k];
  }
  __syncthreads();   // wend + B/C/Xt ready

  // stage B̃^T[n][j] = wend_j * B[j][n]
  #pragma unroll
  for (int u=0; u<2; ++u) {
    int q = tid + 256*u;
    int j = q >> 4, n8 = (q & 15)*8;
    const float w = s_wend[j];
    U4S8 bv; bv.v = *(const uint4*)(rowbase + (size_t)j*CONV_DIM + D_INNER + n8);
    #pragma unroll
    for (int k=0;k<8;k++)
      *(unsigned short*)(Btb + ((n8+k)*48 + j)*2) = bf16bits(bf2f(bv.s[k]) * w);
  }

  const int lane = tid & 63;
  const int w    = tid >> 6;
  const int lrow = lane & 15;
  const int lkb  = (lane >> 4) * 16;
  // ---- G phase ----
  {
    const int wi = w >> 1, wj = w & 1;
    f32x4 g = (f32x4){0.f,0.f,0.f,0.f};
    const char* Ar = Cb + (wi*16 + lrow)*272 + lkb;
    const char* Br = Bb + (wj*16 + lrow)*272 + lkb;
    #pragma unroll
    for (int ks=0; ks<4; ks++){
      short8 a  = *(const short8*)(Ar + ks*64);
      short8 bb = *(const short8*)(Br + ks*64);
      g = __builtin_amdgcn_mfma_f32_16x16x32_bf16(a, bb, g, 0,0,0);
    }
    const int j = wj*16 + lrow;
    const float lcj = s_lc[j], dtj = s_dt[j];
    const float dsk = D_skip[h];
    const int i0 = wi*16 + (lane>>4)*4;
    #pragma unroll
    for (int r=0;r<4;r++){
      int i = i0 + r;
      float m = 0.f;
      if (j <= i) { m = g[r]*expf(s_lc[i]-lcj)*dtj; if (j==i) m += dsk; }
      *(unsigned short*)(Mb + (i*48 + j)*2) = bf16bits(m);
    }
  }
  __syncthreads();   // M̃ ready

  // ---- Y phase ----
  {
    const int it = w >> 1;
    const int pb = (w & 1)*2;
    short8 am = *(const short8*)(Mb + (it*16+lrow)*96 + lkb);
    float* ybase = y + ((size_t)(b*SEQ+t0))*D_INNER + h*HEADDIM;
    #pragma unroll
    for (int pi=0; pi<2; pi++){
      short8 xv = *(const short8*)(Xtb + ((pb+pi)*16+lrow)*96 + lkb);
      f32x4 ya = __builtin_amdgcn_mfma_f32_16x16x32_bf16(am, xv, (f32x4){0.f,0.f,0.f,0.f}, 0,0,0);
      #pragma unroll
      for (int r=0;r<4;r++){
        int i = it*16 + (lane>>4)*4 + r;
        ybase[(size_t)i*D_INNER + (pb+pi)*16 + lrow] = ya[r];
      }
    }
  }

  // ---- S phase ----
  f32x4 sacc[8];
  {
    short8 ax = *(const short8*)(Xtb + (w*16+lrow)*96 + lkb);
    #pragma unroll
    for (int nt=0;nt<8;nt++){
      short8 bv = *(const short8*)(Btb + (nt*16+lrow)*96 + lkb);
      sacc[nt] = __builtin_amdgcn_mfma_f32_16x16x32_bf16(ax, bv, (f32x4){0.f,0.f,0.f,0.f}, 0,0,0);
    }
  }
  __syncthreads();
  {
    const int p0b = w*16 + (lane>>4)*4;
    #pragma unroll
    for (int nt=0;nt<8;nt++){
      int n = nt*16 + lrow;
      #pragma unroll
      for (int r=0;r<4;r++)
        *(unsigned short*)(sm + (p0b+r)*272 + n*2) = bf16bits(sacc[nt][r]);
    }
  }
  __syncthreads();
  __hip_bfloat16* Sout = Sbuf + (size_t)cid*(D_STATE*HEADDIM);
  #pragma unroll
  for (int u=0;u<4;u++){
    int q = tid*4+u, row = q>>4, c8 = (q&15)*8;
    *(uint4*)(Sout + row*128 + c8) = *(const uint4*)(sm + row*272 + c8*2);
  }
}

// Kernel B: serial inter-chunk recurrence, 128 blocks, uint4 slices.
__global__ __launch_bounds__(256)
void state_scan(__hip_bfloat16* __restrict__ Sbuf, const float* __restrict__ lcend)
{
  const int bh = blockIdx.x >> 2;
  const int sl = blockIdx.x & 3;
  const int tid = threadIdx.x;
  uint4* Sb4 = (uint4*)Sbuf;
  const int idx0 = bh*NCHUNK*1024 + sl*256 + tid;

  float H[8];
  #pragma unroll
  for (int r=0;r<8;r++) H[r]=0.f;
  uint4 cur = Sb4[idx0];
  float lcv = lcend[bh*NCHUNK];
  for (int c=0;c<NCHUNK;c++){
    uint4 nxt; float lcn;
    if (c < NCHUNK-1) { nxt = Sb4[idx0 + (c+1)*1024]; lcn = lcend[bh*NCHUNK + c + 1]; }
    else              { nxt = make_uint4(0,0,0,0);    lcn = 0.f; }
    float e = expf(lcv);
    uint4 o;
    o.x = bfpack2(H[0],H[1]); o.y = bfpack2(H[2],H[3]);
    o.z = bfpack2(H[4],H[5]); o.w = bfpack2(H[6],H[7]);
    Sb4[idx0 + c*1024] = o;
    H[0]=e*H[0]+blo(cur.x); H[1]=e*H[1]+bhi(cur.x);
    H[2]=e*H[2]+blo(cur.y); H[3]=e*H[3]+bhi(cur.y);
    H[4]=e*H[4]+blo(cur.z); H[5]=e*H[5]+bhi(cur.z);
    H[6]=e*H[6]+blo(cur.w); H[7]=e*H[7]+bhi(cur.w);
    cur = nxt; lcv = lcn;
  }
}

// Kernel C (MFMA): y += scl_i * C_i @ H_prev.  H stored as H^T[p][n].
__global__ __launch_bounds__(256)
void chunk_inter(const __hip_bfloat16* __restrict__ xbc, const __hip_bfloat16* __restrict__ Sbuf,
                 const float* __restrict__ scl, float* __restrict__ y)
{
  __shared__ char sm2[8704 + 17408];
  __shared__ float s_scl[LCH];
  char* Cb = sm2;
  char* Ht = sm2 + 8704;
  const int cid = blockIdx.x;
  const int c  = cid & (NCHUNK-1);
  const int bh = cid >> 6;
  const int h  = bh & 15;
  const int b  = bh >> 4;
  const int tid = threadIdx.x;
  const int t0 = c*LCH;
  const __hip_bfloat16* rowbase = xbc + ((size_t)(b*SEQ + t0))*CONV_DIM;

  #pragma unroll
  for (int u=0;u<2;u++){
    int q = tid + 256*u;
    int r = q >> 4, c8 = (q & 15)*8;
    *(uint4*)(Cb + r*272 + c8*2) = *(const uint4*)(rowbase + (size_t)r*CONV_DIM + D_INNER + D_STATE + c8);
  }
  const uint4* Hin = (const uint4*)(Sbuf + (size_t)cid*(D_STATE*HEADDIM));
  #pragma unroll
  for (int u=0;u<4;u++){
    int q = tid*4+u, row = q>>4, c8 = (q&15)*8;
    *(uint4*)(Ht + row*272 + c8*2) = Hin[q];
  }
  if (tid < 32) s_scl[tid] = scl[cid*LCH + tid];
  __syncthreads();

  const int lane = tid & 63;
  const int w    = tid >> 6;
  const int lrow = lane & 15;
  const int lkb  = (lane >> 4) * 16;
  const int it   = w >> 1;
  const int pb   = (w & 1)*2;
  f32x4 acc[2];
  acc[0] = (f32x4){0.f,0.f,0.f,0.f};
  acc[1] = (f32x4){0.f,0.f,0.f,0.f};
  const char* Ar = Cb + (it*16+lrow)*272 + lkb;
  const char* H0 = Ht + ((pb+0)*16+lrow)*272 + lkb;
  const char* H1 = Ht + ((pb+1)*16+lrow)*272 + lkb;
  #pragma unroll
  for (int ks=0; ks<4; ks++){
    short8 a  = *(const short8*)(Ar + ks*64);
    short8 h0 = *(const short8*)(H0 + ks*64);
    short8 h1 = *(const short8*)(H1 + ks*64);
    acc[0] = __builtin_amdgcn_mfma_f32_16x16x32_bf16(a, h0, acc[0], 0,0,0);
    acc[1] = __builtin_amdgcn_mfma_f32_16x16x32_bf16(a, h1, acc[1], 0,0,0);
  }
  float* ybase = y + ((size_t)(b*SEQ+t0))*D_INNER + h*HEADDIM;
  #pragma unroll
  for (int pi=0; pi<2; pi++){
    #pragma unroll
    for (int r=0;r<4;r++){
      int i = it*16 + (lane>>4)*4 + r;
      float* yp = ybase + (size_t)i*D_INNER + (pb+pi)*16 + lrow;
      *yp += s_scl[i]*acc[pi][r];
    }
  }
}

// -------- y*silu(z), RMSNorm(1024)*gnorm_w -> bf16 out -----------------------
__global__ __launch_bounds__(256)
void gate_rms(const float* __restrict__ zx, const float* __restrict__ gw,
              const float* __restrict__ yin, __hip_bfloat16* __restrict__ ybf)
{
  int tok = blockIdx.x;
  const float* z = zx + (size_t)tok*D_IN_PROJ;
  const float* yr = yin + (size_t)tok*D_INNER;
  __hip_bfloat16* yo = ybf + (size_t)tok*D_INNER;
  float g[4];
  float ss = 0.f;
  #pragma unroll
  for (int i=0;i<4;i++) {
    int c = i*256 + threadIdx.x;
    float zv = z[c];
    float gv = yr[c] * (zv * sigmoid_f(zv));
    g[i]=gv; ss += gv*gv;
  }
  #pragma unroll
  for (int m=32;m>=1;m>>=1) ss += __shfl_xor(ss, m, 64);
  __shared__ float red[4];
  int wv = threadIdx.x >> 6;
  if ((threadIdx.x & 63)==0) red[wv]=ss;
  __syncthreads();
  float tot = red[0]+red[1]+red[2]+red[3];
  float sc = rsqrtf(tot*(1.f/1024.f) + 1e-5f);
  #pragma unroll
  for (int i=0;i<4;i++) {
    int c = i*256 + threadIdx.x;
    yo[c] = __float2bfloat16(g[i]*sc*gw[c]);
  }
}

// ---------------- out = LayerNorm(a + b); optional bf16 copy -----------------
template<int WBF>
__global__ __launch_bounds__(256)
void add_ln(const float* __restrict__ a, const float* __restrict__ bres,
            const float* __restrict__ gg, const float* __restrict__ bb,
            float* __restrict__ out, __hip_bfloat16* __restrict__ outbf)
{
  int tok = blockIdx.x;
  size_t o = (size_t)tok*D_MODEL;
  int c0 = threadIdx.x, c1 = threadIdx.x + 256;
  float v0 = a[o+c0] + bres[o+c0];
  float v1 = a[o+c1] + bres[o+c1];
  float s = v0+v1, sq = v0*v0+v1*v1;
  #pragma unroll
  for (int m=32;m>=1;m>>=1){ s += __shfl_xor(s,m,64); sq += __shfl_xor(sq,m,64); }
  __shared__ float rs[4], rq[4];
  int wv = threadIdx.x>>6;
  if ((threadIdx.x&63)==0){ rs[wv]=s; rq[wv]=sq; }
  __syncthreads();
  float S = rs[0]+rs[1]+rs[2]+rs[3];
  float Q = rq[0]+rq[1]+rq[2]+rq[3];
  float mean = S*(1.f/512.f);
  float var  = Q*(1.f/512.f) - mean*mean;
  float inv  = rsqrtf(var + 1e-5f);
  float o0 = (v0-mean)*inv*gg[c0] + bb[c0];
  float o1 = (v1-mean)*inv*gg[c1] + bb[c1];
  out[o+c0] = o0;
  out[o+c1] = o1;
  if (WBF) { outbf[o+c0] = __float2bfloat16(o0); outbf[o+c1] = __float2bfloat16(o1); }
}

extern "C" void kernel_launch(void* const* d_in, const int* in_sizes, int n_in,
                              void* d_out, int out_size, void* d_ws, size_t ws_size,
                              hipStream_t stream)
{
  const float* tgt    = (const float*)d_in[0];
  const float* W_in   = (const float*)d_in[1];
  const float* conv_w = (const float*)d_in[2];
  const float* conv_b = (const float*)d_in[3];
  const float* dt_bias= (const float*)d_in[4];
  const float* A_log  = (const float*)d_in[5];
  const float* D_skip = (const float*)d_in[6];
  const float* gnorm_w= (const float*)d_in[7];
  const float* W_out  = (const float*)d_in[8];
  const float* n1_g   = (const float*)d_in[9];
  const float* n1_b   = (const float*)d_in[10];
  const float* ffn_w1 = (const float*)d_in[11];
  const float* ffn_b1 = (const float*)d_in[12];
  const float* ffn_w2 = (const float*)d_in[13];
  const float* ffn_b2 = (const float*)d_in[14];
  const float* n3_g   = (const float*)d_in[15];
  const float* n3_b   = (const float*)d_in[16];
  float* out = (float*)d_out;
  float* ws  = (float*)d_ws;

  // ---- workspace layout (float offsets) ----
  float* zx   = ws;                                   // 9,502,720
  float* xbcF = zx  + (size_t)NTOK*D_IN_PROJ;         // xbc: bf16 NTOK*1280 -> 2,621,440 floats
  __hip_bfloat16* xbc = (__hip_bfloat16*)xbcF;
  float* dtp  = xbcF + 2621440;                       // 65,536
  float* yb   = dtp + (size_t)NTOK*16;                // 4,194,304
  float* Sreg = yb  + (size_t)NTOK*D_INNER;           // 8,388,608 (Sbuf bf16)
  __hip_bfloat16* Sbuf = (__hip_bfloat16*)Sreg;
  float* lcend= Sreg + 8388608;                       // 2048
  float* scl  = lcend + NCID;                         // 65,536

  // aliases into dead regions
  __hip_bfloat16* tgt_bf = (__hip_bfloat16*)yb;                 // dead until chunk_intra
  __hip_bfloat16* Wint   = (__hip_bfloat16*)Sreg;               // [2432][512], used step 1
  __hip_bfloat16* yb_bf  = (__hip_bfloat16*)xbcF;               // xbc dead after chunk_inter
  __hip_bfloat16* tb_bf  = (__hip_bfloat16*)(yb + 2097152);     // yb dead after gate_rms
  float* tb   = Sreg;                                           // Sbuf dead after chunk_inter
  float* tmp  = Sreg + 2097152;
  __hip_bfloat16* Woutt  = (__hip_bfloat16*)(Sreg + 4194304);   // [512][1024]
  __hip_bfloat16* W1t    = (__hip_bfloat16*)(Sreg + 4194304 + 262144);   // [2048][512]
  __hip_bfloat16* W2t    = (__hip_bfloat16*)(Sreg + 4194304 + 262144 + 524288); // [512][2048]
  __hip_bfloat16* hmid_bf= (__hip_bfloat16*)zx;                 // zx dead after gate_rms

  // 0) weight prep + tgt->bf16
  transpose_to_bf16<<<dim3(NPJ_PAD/32, D_MODEL/32), 256, 0, stream>>>(W_in, Wint, D_MODEL, D_IN_PROJ, NPJ_PAD);
  f32_to_bf16_k<<<(NTOK*D_MODEL)/1024, 256, 0, stream>>>(tgt, tgt_bf, NTOK*D_MODEL);
  // 1) in-proj (128x128 m97 structure)
  gemm128<0,float><<<dim3(NPJ_PAD/128, NTOK/128), 256, 0, stream>>>(
      tgt_bf, Wint, nullptr, zx, D_IN_PROJ, D_MODEL, D_IN_PROJ);
  // 2) conv + SiLU -> bf16 xbc (+ fused dt)
  conv_silu<<<dim3(CONV_DIM/256, SEQ/64, B_SZ), 256, 0, stream>>>(zx, conv_w, conv_b, xbc, dt_bias, dtp);
  // 3) chunked scan
  chunk_intra<<<NCID, 256, 0, stream>>>(xbc, dtp, A_log, D_skip, yb, Sbuf, lcend, scl);
  state_scan<<<B_SZ*NHEADS*4, 256, 0, stream>>>(Sbuf, lcend);
  chunk_inter<<<NCID, 256, 0, stream>>>(xbc, Sbuf, scl, yb);
  // 3d) remaining weight transposes (Sbuf dead)
  transpose_to_bf16<<<dim3(D_MODEL/32, D_INNER/32), 256, 0, stream>>>(W_out, Woutt, D_INNER, D_MODEL, D_MODEL);
  transpose_to_bf16<<<dim3(FF/32, D_MODEL/32), 256, 0, stream>>>(ffn_w1, W1t, D_MODEL, FF, FF);
  transpose_to_bf16<<<dim3(D_MODEL/32, FF/32), 256, 0, stream>>>(ffn_w2, W2t, FF, D_MODEL, D_MODEL);
  // 4) gate + RMSNorm -> bf16
  gate_rms<<<NTOK, 256, 0, stream>>>(zx, gnorm_w, yb, yb_bf);
  // 5) out-proj (128x64: 256 blocks)
  gemm_bf16<0,float><<<dim3(D_MODEL/64, NTOK/128), 256, 0, stream>>>(
      yb_bf, Woutt, nullptr, tmp, D_MODEL, D_INNER, D_MODEL);
  // 6) tb = LayerNorm(tmp + tgt) (+ bf16 copy)
  add_ln<1><<<NTOK, 256, 0, stream>>>(tmp, tgt, n1_g, n1_b, tb, tb_bf);
  // 7) ffn1 (128x128) -> bf16 hmid
  gemm128<2,__hip_bfloat16><<<dim3(FF/128, NTOK/128), 256, 0, stream>>>(
      tb_bf, W1t, ffn_b1, hmid_bf, FF, D_MODEL, FF);
  // 8) ffn2 (128x64)
  gemm_bf16<1,float><<<dim3(D_MODEL/64, NTOK/128), 256, 0, stream>>>(
      hmid_bf, W2t, ffn_b2, tmp, D_MODEL, FF, D_MODEL);
  // 9) out = LayerNorm(tmp + tb)
  add_ln<0><<<NTOK, 256, 0, stream>>>(tmp, tb, n3_g, n3_b, out, nullptr);
}

// Round 7
// 181.215 us; speedup vs baseline: 8.1655x; 1.1697x over previous
//
#include <hip/hip_runtime.h>
#include <hip/hip_bf16.h>
#include <cstddef>
#include <cstdint>

#define D_MODEL   512
#define FF        2048
#define D_STATE   128
#define D_INNER   1024
#define HEADDIM   64
#define NHEADS    16
#define CONV_DIM  1280
#define D_IN_PROJ 2320
#define NPJ_PAD   2432      // D_IN_PROJ padded to 128
#define B_SZ      2
#define SEQ       2048
#define NTOK      (B_SZ*SEQ)   // 4096
#define LCH       32
#define NCHUNK    (SEQ/LCH)    // 64
#define NCID      (B_SZ*NHEADS*NCHUNK)  // 2048

typedef __attribute__((ext_vector_type(8))) short short8;
typedef __attribute__((ext_vector_type(4))) float f32x4;

__device__ __forceinline__ float sigmoid_f(float x){ return 1.0f/(1.0f+expf(-x)); }
__device__ __forceinline__ float gelu_f(float x){ return 0.5f*x*(1.0f+erff(x*0.70710678118654752f)); }

__device__ __forceinline__ unsigned short bf16bits(float f){
  __hip_bfloat16 h = __float2bfloat16(f);
  return *reinterpret_cast<unsigned short*>(&h);
}
__device__ __forceinline__ float bf2f(unsigned short u){ return __uint_as_float(((unsigned)u)<<16); }
__device__ __forceinline__ float blo(unsigned u){ return __uint_as_float(u<<16); }
__device__ __forceinline__ float bhi(unsigned u){ return __uint_as_float(u & 0xffff0000u); }
__device__ __forceinline__ unsigned bfpack2(float a, float b){
  return (unsigned)bf16bits(a) | ((unsigned)bf16bits(b)<<16);
}

__device__ __forceinline__ void gload16(const void* g, void* l){
  __builtin_amdgcn_global_load_lds((const __attribute__((address_space(1))) void*)g,
                                   (__attribute__((address_space(3))) void*)l, 16, 0, 0);
}

union U4S8 { uint4 v; unsigned short s[8]; };

// ============ m97-structure GEMM: BM=128,BN=128,BK=64, 4 waves of 64x64 ======
template<int EPI, typename OT>   // EPI 0: none, 1: +bias, 2: gelu(.+bias)
__global__ __launch_bounds__(256)
void gemm128(const __hip_bfloat16* __restrict__ A, const __hip_bfloat16* __restrict__ Bt,
             const float* __restrict__ bias, OT* __restrict__ C,
             int N, int K, int ldc)
{
  __shared__ char AsRaw[128*128];
  __shared__ char BsRaw[128*128];

  const int t    = threadIdx.x;
  const int bm   = blockIdx.y * 128;
  const int bn   = blockIdx.x * 128;
  const int lane = t & 63;
  const int wid  = t >> 6;
  const int wr   = wid >> 1;
  const int wc   = wid & 1;
  const int lrow = lane & 15;
  const int lkb  = (lane >> 4) * 16;
  const int sw   = (lrow & 7) << 4;

  const int rA  = t >> 3;
  const int cbA = (t & 7) * 16;
  const int scb = cbA ^ ((rA & 7) << 4);
  const size_t strideA = (size_t)K * 2;
  const char* aSrc = (const char*)A  + (size_t)(bm + rA) * strideA + scb;
  const char* bSrc = (const char*)Bt + (size_t)(bn + rA) * strideA + scb;
  char* aDst = AsRaw + wid * 1024;
  char* bDst = BsRaw + wid * 1024;

  f32x4 acc[4][4];
  #pragma unroll
  for (int m=0;m<4;m++)
    #pragma unroll
    for (int n=0;n<4;n++) acc[m][n] = (f32x4){0.f,0.f,0.f,0.f};

  const char* ArP = AsRaw + (wr*64 + lrow) * 128;
  const char* BrP = BsRaw + (wc*64 + lrow) * 128;

  for (int k0 = 0; k0 < K; k0 += 64) {
    const size_t ko = (size_t)k0 * 2;
    gload16(aSrc + ko,               aDst);
    gload16(aSrc + ko + 32*strideA,  aDst + 4096);
    gload16(aSrc + ko + 64*strideA,  aDst + 8192);
    gload16(aSrc + ko + 96*strideA,  aDst + 12288);
    gload16(bSrc + ko,               bDst);
    gload16(bSrc + ko + 32*strideA,  bDst + 4096);
    gload16(bSrc + ko + 64*strideA,  bDst + 8192);
    gload16(bSrc + ko + 96*strideA,  bDst + 12288);
    __syncthreads();
    #pragma unroll
    for (int kk = 0; kk < 2; ++kk) {
      const int kb = (kk*64 + lkb) ^ sw;
      short8 a0 = *(const short8*)(ArP + 0*2048 + kb);
      short8 a1 = *(const short8*)(ArP + 1*2048 + kb);
      short8 a2 = *(const short8*)(ArP + 2*2048 + kb);
      short8 a3 = *(const short8*)(ArP + 3*2048 + kb);
      short8 b0 = *(const short8*)(BrP + 0*2048 + kb);
      short8 b1 = *(const short8*)(BrP + 1*2048 + kb);
      short8 b2 = *(const short8*)(BrP + 2*2048 + kb);
      short8 b3 = *(const short8*)(BrP + 3*2048 + kb);
      #pragma unroll
      for (int m=0;m<4;m++){
        short8 am = (m==0)?a0:(m==1)?a1:(m==2)?a2:a3;
        acc[m][0] = __builtin_amdgcn_mfma_f32_16x16x32_bf16(am, b0, acc[m][0], 0,0,0);
        acc[m][1] = __builtin_amdgcn_mfma_f32_16x16x32_bf16(am, b1, acc[m][1], 0,0,0);
        acc[m][2] = __builtin_amdgcn_mfma_f32_16x16x32_bf16(am, b2, acc[m][2], 0,0,0);
        acc[m][3] = __builtin_amdgcn_mfma_f32_16x16x32_bf16(am, b3, acc[m][3], 0,0,0);
      }
    }
    __syncthreads();
  }

  const int orow0 = bm + wr*64 + (lane >> 4) * 4;
  const int ocol0 = bn + wc*64 + lrow;
  #pragma unroll
  for (int n=0;n<4;n++) {
    const int col = ocol0 + n*16;
    if (col >= N) continue;
    const float bv = (EPI>=1) ? bias[col] : 0.f;
    #pragma unroll
    for (int m=0;m<4;m++) {
      #pragma unroll
      for (int j=0;j<4;j++) {
        float v = acc[m][n][j] + bv;
        if (EPI==2) v = gelu_f(v);
        OT* cp = C + (size_t)(orow0 + m*16 + j)*ldc + col;
        if constexpr (sizeof(OT)==2) *cp = __float2bfloat16(v); else *cp = v;
      }
    }
  }
}

// ==== 128x64 GEMM with split-K (blockIdx.z): C_z = A[:,zK/s:(z+1)K/s]@Bt^T ====
template<int EPI, typename OT>
__global__ __launch_bounds__(256)
void gemm_bf16(const __hip_bfloat16* __restrict__ A, const __hip_bfloat16* __restrict__ Bt,
               const float* __restrict__ bias, OT* __restrict__ C,
               int N, int K, int ldc, int M, int nsplit)
{
  __shared__ char AsRaw[128*128];
  __shared__ char BsRaw[64*128];

  const int t    = threadIdx.x;
  const int bm   = blockIdx.y * 128;
  const int bn   = blockIdx.x * 64;
  const int z    = blockIdx.z;
  const int Kloop= K / nsplit;
  A += (size_t)z * Kloop;
  Bt += (size_t)z * Kloop;
  C += (size_t)z * M * ldc;

  const int lane = t & 63;
  const int wid  = t >> 6;
  const int wr   = wid >> 1;
  const int wc   = wid & 1;
  const int lrow = lane & 15;
  const int lkb  = (lane >> 4) * 16;
  const int sw   = (lrow & 7) << 4;

  const int rA  = t >> 3;
  const int cbA = (t & 7) * 16;
  const int scb = cbA ^ ((rA & 7) << 4);
  const size_t strideA = (size_t)K * 2;
  const char* aSrc = (const char*)A  + (size_t)(bm + rA) * strideA + scb;
  const char* bSrc = (const char*)Bt + (size_t)(bn + rA) * strideA + scb;
  char* aDst = AsRaw + wid * 1024;
  char* bDst = BsRaw + wid * 1024;

  f32x4 acc[4][2];
  #pragma unroll
  for (int m=0;m<4;m++)
    #pragma unroll
    for (int n=0;n<2;n++) acc[m][n] = (f32x4){0.f,0.f,0.f,0.f};

  const char* ArP = AsRaw + (wr*64 + lrow) * 128;
  const char* BrP = BsRaw + (wc*32 + lrow) * 128;

  for (int k0 = 0; k0 < Kloop; k0 += 64) {
    const size_t ko = (size_t)k0 * 2;
    gload16(aSrc + ko,               aDst);
    gload16(aSrc + ko + 32*strideA,  aDst + 4096);
    gload16(aSrc + ko + 64*strideA,  aDst + 8192);
    gload16(aSrc + ko + 96*strideA,  aDst + 12288);
    gload16(bSrc + ko,               bDst);
    gload16(bSrc + ko + 32*strideA,  bDst + 4096);
    __syncthreads();
    #pragma unroll
    for (int kk = 0; kk < 2; ++kk) {
      const int kb = (kk*64 + lkb) ^ sw;
      short8 a0 = *(const short8*)(ArP + 0*2048 + kb);
      short8 a1 = *(const short8*)(ArP + 1*2048 + kb);
      short8 a2 = *(const short8*)(ArP + 2*2048 + kb);
      short8 a3 = *(const short8*)(ArP + 3*2048 + kb);
      short8 b0 = *(const short8*)(BrP + 0*2048 + kb);
      short8 b1 = *(const short8*)(BrP + 1*2048 + kb);
      acc[0][0] = __builtin_amdgcn_mfma_f32_16x16x32_bf16(a0, b0, acc[0][0], 0,0,0);
      acc[1][0] = __builtin_amdgcn_mfma_f32_16x16x32_bf16(a1, b0, acc[1][0], 0,0,0);
      acc[2][0] = __builtin_amdgcn_mfma_f32_16x16x32_bf16(a2, b0, acc[2][0], 0,0,0);
      acc[3][0] = __builtin_amdgcn_mfma_f32_16x16x32_bf16(a3, b0, acc[3][0], 0,0,0);
      acc[0][1] = __builtin_amdgcn_mfma_f32_16x16x32_bf16(a0, b1, acc[0][1], 0,0,0);
      acc[1][1] = __builtin_amdgcn_mfma_f32_16x16x32_bf16(a1, b1, acc[1][1], 0,0,0);
      acc[2][1] = __builtin_amdgcn_mfma_f32_16x16x32_bf16(a2, b1, acc[2][1], 0,0,0);
      acc[3][1] = __builtin_amdgcn_mfma_f32_16x16x32_bf16(a3, b1, acc[3][1], 0,0,0);
    }
    __syncthreads();
  }

  const int orow0 = bm + wr*64 + (lane >> 4) * 4;
  const int ocol0 = bn + wc*32 + lrow;
  #pragma unroll
  for (int n=0;n<2;n++) {
    const int col = ocol0 + n*16;
    if (col >= N) continue;
    const float bv = (EPI>=1 && z==0) ? bias[col] : 0.f;
    #pragma unroll
    for (int m=0;m<4;m++) {
      #pragma unroll
      for (int j=0;j<4;j++) {
        float v = acc[m][n][j] + bv;
        if (EPI==2) v = gelu_f(v);
        OT* cp = C + (size_t)(orow0 + m*16 + j)*ldc + col;
        if constexpr (sizeof(OT)==2) *cp = __float2bfloat16(v); else *cp = v;
      }
    }
  }
}

// ======= prep_all: all 4 weight transposes + tgt->bf16 in ONE dispatch =======
__device__ __forceinline__ void tr_tile(const float* __restrict__ in,
                                        __hip_bfloat16* __restrict__ out,
                                        int K, int N, int Npad, int bx, int by)
{
  __shared__ float tbuf[32][33];
  const int tx = threadIdx.x & 31, ty = threadIdx.x >> 5;
  #pragma unroll
  for (int u=0;u<4;u++){
    int k = by*32 + ty + u*8;
    int n = bx*32 + tx;
    tbuf[ty+u*8][tx] = (n < N) ? in[(size_t)k*N + n] : 0.f;
  }
  __syncthreads();
  #pragma unroll
  for (int u=0;u<4;u++){
    int n = bx*32 + ty + u*8;
    int k = by*32 + tx;
    if (n < Npad) out[(size_t)n*K + k] = __float2bfloat16(tbuf[tx][ty+u*8]);
  }
}

__global__ __launch_bounds__(256)
void prep_all(const float* __restrict__ tgt, __hip_bfloat16* __restrict__ tgt_bf,
              const float* __restrict__ W_in,  __hip_bfloat16* __restrict__ Wint,
              const float* __restrict__ W_out, __hip_bfloat16* __restrict__ Woutt,
              const float* __restrict__ W1,    __hip_bfloat16* __restrict__ W1t,
              const float* __restrict__ W2,    __hip_bfloat16* __restrict__ W2t)
{
  int bid = blockIdx.x;
  if (bid < 2048) {             // tgt convert: 2M elems, 1024/block
    int i = bid*1024 + threadIdx.x*4;
    float4 v = *(const float4*)(tgt + i);
    *(uint2*)(tgt_bf + i) = (uint2){bfpack2(v.x,v.y), bfpack2(v.z,v.w)};
    return;
  }
  bid -= 2048;
  if (bid < 76*16) { tr_tile(W_in, Wint, D_MODEL, D_IN_PROJ, NPJ_PAD, bid%76, bid/76); return; }
  bid -= 76*16;
  if (bid < 16*32) { tr_tile(W_out, Woutt, D_INNER, D_MODEL, D_MODEL, bid%16, bid/16); return; }
  bid -= 16*32;
  if (bid < 64*16) { tr_tile(W1, W1t, D_MODEL, FF, FF, bid%64, bid/64); return; }
  bid -= 64*16;
  tr_tile(W2, W2t, FF, D_MODEL, D_MODEL, bid%16, bid/16);
}

// ------- depthwise causal conv(4)+SiLU -> bf16 xbc; block x==0 also does dt --
__global__ __launch_bounds__(256)
void conv_silu(const float* __restrict__ zx, const float* __restrict__ cw,
               const float* __restrict__ cb, __hip_bfloat16* __restrict__ xbc,
               const float* __restrict__ dt_bias, float* __restrict__ dtp)
{
  const int c  = blockIdx.x*256 + threadIdx.x;     // 0..1279
  const int t0 = blockIdx.y*64;
  const int b  = blockIdx.z;
  const float w0=cw[c*4+0], w1=cw[c*4+1], w2=cw[c*4+2], w3=cw[c*4+3];
  const float cbv = cb[c];
  const float* base = zx + ((size_t)(b*SEQ + t0))*D_IN_PROJ + D_INNER + c;
  __hip_bfloat16* obase = xbc + ((size_t)(b*SEQ + t0))*CONV_DIM + c;
  float xm3, xm2, xm1;
  if (t0 == 0) { xm3 = 0.f; xm2 = 0.f; xm1 = 0.f; }
  else {
    xm3 = base[-3*(ptrdiff_t)D_IN_PROJ];
    xm2 = base[-2*(ptrdiff_t)D_IN_PROJ];
    xm1 = base[-1*(ptrdiff_t)D_IN_PROJ];
  }
  #pragma unroll 4
  for (int t=0; t<64; ++t) {
    float xc = base[(size_t)t*D_IN_PROJ];
    float acc = cbv + w0*xm3 + w1*xm2 + w2*xm1 + w3*xc;
    obase[(size_t)t*CONV_DIM] = __float2bfloat16(acc * sigmoid_f(acc));
    xm3 = xm2; xm2 = xm1; xm1 = xc;
  }
  if (blockIdx.x == 0) {
    #pragma unroll
    for (int it=0; it<4; ++it) {
      int idx = it*256 + threadIdx.x;
      int tloc = idx >> 4, hh = idx & 15;
      int tok = b*SEQ + t0 + tloc;
      float x = zx[(size_t)tok*D_IN_PROJ + (D_INNER + CONV_DIM) + hh] + dt_bias[hh];
      float sp = (x > 20.f) ? x : log1pf(expf(x));
      dtp[tok*16 + hh] = sp;
    }
  }
}

// ============== chunked SSD scan — MFMA version (bf16 xbc) ====================
__global__ __launch_bounds__(256)
void chunk_intra(const __hip_bfloat16* __restrict__ xbc, const float* __restrict__ dtp,
                 const float* __restrict__ A_log, const float* __restrict__ D_skip,
                 float* __restrict__ y, __hip_bfloat16* __restrict__ Sbuf,
                 float* __restrict__ lcend, float* __restrict__ scl)
{
  __shared__ char sm[38912];
  __shared__ float s_dt[LCH], s_lc[LCH], s_wend[LCH];
  char* Cb  = sm;            // [32] rows x 272B   (8704)
  char* Bb  = sm + 8704;     // [32] x 272B        (8704)
  char* Btb = sm + 17408;    // [128] rows x 96B   (12288)  B̃^T[n][j]
  char* Xtb = sm + 29696;    // [64] rows x 96B    (6144)   X^T[p][j]
  char* Mb  = sm + 35840;    // [32] rows x 96B    (3072)   M̃[i][j]

  const int cid = blockIdx.x;
  const int c  = cid & (NCHUNK-1);
  const int bh = cid >> 6;
  const int h  = bh & 15;
  const int b  = bh >> 4;
  const int tid = threadIdx.x;
  const int t0 = c*LCH;
  const __hip_bfloat16* rowbase = xbc + ((size_t)(b*SEQ + t0))*CONV_DIM;

  if (tid < 32) {
    float A_h = -expf(A_log[h]);
    float dtv = dtp[((size_t)(b*SEQ + t0 + tid))*16 + h];
    float lc = dtv * A_h;
    #pragma unroll
    for (int d=1; d<32; d<<=1) {
      float o = __shfl_up(lc, d, 32);
      if (tid >= d) lc += o;
    }
    float lc31 = __shfl(lc, 31, 32);
    s_dt[tid] = dtv;
    s_lc[tid] = lc;
    s_wend[tid] = expf(lc31 - lc) * dtv;
    scl[cid*LCH + tid] = expf(lc);
    if (tid == 31) lcend[cid] = lc;
  }

  #pragma unroll
  for (int u=0; u<2; ++u) {
    int q = tid + 256*u;
    int r = q >> 4, c8 = (q & 15)*8;
    const __hip_bfloat16* rp = rowbase + (size_t)r*CONV_DIM + D_INNER;
    *(uint4*)(Bb + r*272 + c8*2) = *(const uint4*)(rp + c8);
    *(uint4*)(Cb + r*272 + c8*2) = *(const uint4*)(rp + D_STATE + c8);
  }
  {
    int j = tid >> 3, p0 = (tid & 7)*8;
    U4S8 xv; xv.v = *(const uint4*)(rowbase + (size_t)j*CONV_DIM + h*HEADDIM + p0);
    #pragma unroll
    for (int k=0;k<8;k++)
      *(unsigned short*)(Xtb + ((p0+k)*48 + j)*2) = xv.s[k];
  }
  __syncthreads();

  #pragma unroll
  for (int u=0; u<2; ++u) {
    int q = tid + 256*u;
    int j = q >> 4, n8 = (q & 15)*8;
    const float w = s_wend[j];
    U4S8 bv; bv.v = *(const uint4*)(rowbase + (size_t)j*CONV_DIM + D_INNER + n8);
    #pragma unroll
    for (int k=0;k<8;k++)
      *(unsigned short*)(Btb + ((n8+k)*48 + j)*2) = bf16bits(bf2f(bv.s[k]) * w);
  }

  const int lane = tid & 63;
  const int w    = tid >> 6;
  const int lrow = lane & 15;
  const int lkb  = (lane >> 4) * 16;
  // ---- G phase ----
  {
    const int wi = w >> 1, wj = w & 1;
    f32x4 g = (f32x4){0.f,0.f,0.f,0.f};
    const char* Ar = Cb + (wi*16 + lrow)*272 + lkb;
    const char* Br = Bb + (wj*16 + lrow)*272 + lkb;
    #pragma unroll
    for (int ks=0; ks<4; ks++){
      short8 a  = *(const short8*)(Ar + ks*64);
      short8 bb = *(const short8*)(Br + ks*64);
      g = __builtin_amdgcn_mfma_f32_16x16x32_bf16(a, bb, g, 0,0,0);
    }
    const int j = wj*16 + lrow;
    const float lcj = s_lc[j], dtj = s_dt[j];
    const float dsk = D_skip[h];
    const int i0 = wi*16 + (lane>>4)*4;
    #pragma unroll
    for (int r=0;r<4;r++){
      int i = i0 + r;
      float m = 0.f;
      if (j <= i) { m = g[r]*expf(s_lc[i]-lcj)*dtj; if (j==i) m += dsk; }
      *(unsigned short*)(Mb + (i*48 + j)*2) = bf16bits(m);
    }
  }
  __syncthreads();

  // ---- Y phase ----
  {
    const int it = w >> 1;
    const int pb = (w & 1)*2;
    short8 am = *(const short8*)(Mb + (it*16+lrow)*96 + lkb);
    float* ybase = y + ((size_t)(b*SEQ+t0))*D_INNER + h*HEADDIM;
    #pragma unroll
    for (int pi=0; pi<2; pi++){
      short8 xv = *(const short8*)(Xtb + ((pb+pi)*16+lrow)*96 + lkb);
      f32x4 ya = __builtin_amdgcn_mfma_f32_16x16x32_bf16(am, xv, (f32x4){0.f,0.f,0.f,0.f}, 0,0,0);
      #pragma unroll
      for (int r=0;r<4;r++){
        int i = it*16 + (lane>>4)*4 + r;
        ybase[(size_t)i*D_INNER + (pb+pi)*16 + lrow] = ya[r];
      }
    }
  }

  // ---- S phase ----
  f32x4 sacc[8];
  {
    short8 ax = *(const short8*)(Xtb + (w*16+lrow)*96 + lkb);
    #pragma unroll
    for (int nt=0;nt<8;nt++){
      short8 bv = *(const short8*)(Btb + (nt*16+lrow)*96 + lkb);
      sacc[nt] = __builtin_amdgcn_mfma_f32_16x16x32_bf16(ax, bv, (f32x4){0.f,0.f,0.f,0.f}, 0,0,0);
    }
  }
  __syncthreads();
  {
    const int p0b = w*16 + (lane>>4)*4;
    #pragma unroll
    for (int nt=0;nt<8;nt++){
      int n = nt*16 + lrow;
      #pragma unroll
      for (int r=0;r<4;r++)
        *(unsigned short*)(sm + (p0b+r)*272 + n*2) = bf16bits(sacc[nt][r]);
    }
  }
  __syncthreads();
  __hip_bfloat16* Sout = Sbuf + (size_t)cid*(D_STATE*HEADDIM);
  #pragma unroll
  for (int u=0;u<4;u++){
    int q = tid*4+u, row = q>>4, c8 = (q&15)*8;
    *(uint4*)(Sout + row*128 + c8) = *(const uint4*)(sm + row*272 + c8*2);
  }
}

// Kernel B: serial inter-chunk recurrence, 128 blocks, prefetch depth 2.
__global__ __launch_bounds__(256)
void state_scan(__hip_bfloat16* __restrict__ Sbuf, const float* __restrict__ lcend)
{
  const int bh = blockIdx.x >> 2;
  const int sl = blockIdx.x & 3;
  const int tid = threadIdx.x;
  uint4* Sb4 = (uint4*)Sbuf;
  const int idx0 = bh*NCHUNK*1024 + sl*256 + tid;

  float H[8];
  #pragma unroll
  for (int r=0;r<8;r++) H[r]=0.f;
  uint4 cur = Sb4[idx0];
  uint4 nx1 = Sb4[idx0 + 1024];
  float lc0 = lcend[bh*NCHUNK];
  float lc1 = lcend[bh*NCHUNK + 1];
  for (int c=0;c<NCHUNK;c++){
    uint4 nx2; float lc2;
    if (c + 2 < NCHUNK) { nx2 = Sb4[idx0 + (c+2)*1024]; lc2 = lcend[bh*NCHUNK + c + 2]; }
    else                { nx2 = make_uint4(0,0,0,0);    lc2 = 0.f; }
    float e = expf(lc0);
    uint4 o;
    o.x = bfpack2(H[0],H[1]); o.y = bfpack2(H[2],H[3]);
    o.z = bfpack2(H[4],H[5]); o.w = bfpack2(H[6],H[7]);
    Sb4[idx0 + c*1024] = o;
    H[0]=e*H[0]+blo(cur.x); H[1]=e*H[1]+bhi(cur.x);
    H[2]=e*H[2]+blo(cur.y); H[3]=e*H[3]+bhi(cur.y);
    H[4]=e*H[4]+blo(cur.z); H[5]=e*H[5]+bhi(cur.z);
    H[6]=e*H[6]+blo(cur.w); H[7]=e*H[7]+bhi(cur.w);
    cur = nx1; nx1 = nx2; lc0 = lc1; lc1 = lc2;
  }
}

// Kernel C (MFMA): y += scl_i * C_i @ H_prev.  H stored as H^T[p][n].
__global__ __launch_bounds__(256)
void chunk_inter(const __hip_bfloat16* __restrict__ xbc, const __hip_bfloat16* __restrict__ Sbuf,
                 const float* __restrict__ scl, float* __restrict__ y)
{
  __shared__ char sm2[8704 + 17408];
  __shared__ float s_scl[LCH];
  char* Cb = sm2;
  char* Ht = sm2 + 8704;
  const int cid = blockIdx.x;
  const int c  = cid & (NCHUNK-1);
  const int bh = cid >> 6;
  const int h  = bh & 15;
  const int b  = bh >> 4;
  const int tid = threadIdx.x;
  const int t0 = c*LCH;
  const __hip_bfloat16* rowbase = xbc + ((size_t)(b*SEQ + t0))*CONV_DIM;

  #pragma unroll
  for (int u=0;u<2;u++){
    int q = tid + 256*u;
    int r = q >> 4, c8 = (q & 15)*8;
    *(uint4*)(Cb + r*272 + c8*2) = *(const uint4*)(rowbase + (size_t)r*CONV_DIM + D_INNER + D_STATE + c8);
  }
  const uint4* Hin = (const uint4*)(Sbuf + (size_t)cid*(D_STATE*HEADDIM));
  #pragma unroll
  for (int u=0;u<4;u++){
    int q = tid*4+u, row = q>>4, c8 = (q&15)*8;
    *(uint4*)(Ht + row*272 + c8*2) = Hin[q];
  }
  if (tid < 32) s_scl[tid] = scl[cid*LCH + tid];
  __syncthreads();

  const int lane = tid & 63;
  const int w    = tid >> 6;
  const int lrow = lane & 15;
  const int lkb  = (lane >> 4) * 16;
  const int it   = w >> 1;
  const int pb   = (w & 1)*2;
  f32x4 acc[2];
  acc[0] = (f32x4){0.f,0.f,0.f,0.f};
  acc[1] = (f32x4){0.f,0.f,0.f,0.f};
  const char* Ar = Cb + (it*16+lrow)*272 + lkb;
  const char* H0 = Ht + ((pb+0)*16+lrow)*272 + lkb;
  const char* H1 = Ht + ((pb+1)*16+lrow)*272 + lkb;
  #pragma unroll
  for (int ks=0; ks<4; ks++){
    short8 a  = *(const short8*)(Ar + ks*64);
    short8 h0 = *(const short8*)(H0 + ks*64);
    short8 h1 = *(const short8*)(H1 + ks*64);
    acc[0] = __builtin_amdgcn_mfma_f32_16x16x32_bf16(a, h0, acc[0], 0,0,0);
    acc[1] = __builtin_amdgcn_mfma_f32_16x16x32_bf16(a, h1, acc[1], 0,0,0);
  }
  float* ybase = y + ((size_t)(b*SEQ+t0))*D_INNER + h*HEADDIM;
  #pragma unroll
  for (int pi=0; pi<2; pi++){
    #pragma unroll
    for (int r=0;r<4;r++){
      int i = it*16 + (lane>>4)*4 + r;
      float* yp = ybase + (size_t)i*D_INNER + (pb+pi)*16 + lrow;
      *yp += s_scl[i]*acc[pi][r];
    }
  }
}

// -------- y*silu(z), RMSNorm(1024)*gnorm_w -> bf16 out (float4 loads) --------
__global__ __launch_bounds__(256)
void gate_rms(const float* __restrict__ zx, const float* __restrict__ gw,
              const float* __restrict__ yin, __hip_bfloat16* __restrict__ ybf)
{
  int tok = blockIdx.x;
  int c = threadIdx.x*4;
  float4 zv = *(const float4*)(zx + (size_t)tok*D_IN_PROJ + c);
  float4 yv = *(const float4*)(yin + (size_t)tok*D_INNER + c);
  float g0 = yv.x * (zv.x * sigmoid_f(zv.x));
  float g1 = yv.y * (zv.y * sigmoid_f(zv.y));
  float g2 = yv.z * (zv.z * sigmoid_f(zv.z));
  float g3 = yv.w * (zv.w * sigmoid_f(zv.w));
  float ss = g0*g0 + g1*g1 + g2*g2 + g3*g3;
  #pragma unroll
  for (int m=32;m>=1;m>>=1) ss += __shfl_xor(ss, m, 64);
  __shared__ float red[4];
  int wv = threadIdx.x >> 6;
  if ((threadIdx.x & 63)==0) red[wv]=ss;
  __syncthreads();
  float tot = red[0]+red[1]+red[2]+red[3];
  float sc = rsqrtf(tot*(1.f/1024.f) + 1e-5f);
  float4 gwv = *(const float4*)(gw + c);
  *(uint2*)(ybf + (size_t)tok*D_INNER + c) =
      (uint2){bfpack2(g0*sc*gwv.x, g1*sc*gwv.y), bfpack2(g2*sc*gwv.z, g3*sc*gwv.w)};
}

// ------ out = LayerNorm(a0 + a1 + bres) over 512; optional bf16 copy ---------
template<int WBF>
__global__ __launch_bounds__(256)
void add_ln(const float* __restrict__ a0p, const float* __restrict__ a1p,
            const float* __restrict__ bres,
            const float* __restrict__ gg, const float* __restrict__ bb,
            float* __restrict__ out, __hip_bfloat16* __restrict__ outbf)
{
  int tok = blockIdx.x;
  size_t o = (size_t)tok*D_MODEL;
  int c0 = threadIdx.x, c1 = threadIdx.x + 256;
  float v0 = a0p[o+c0] + a1p[o+c0] + bres[o+c0];
  float v1 = a0p[o+c1] + a1p[o+c1] + bres[o+c1];
  float s = v0+v1, sq = v0*v0+v1*v1;
  #pragma unroll
  for (int m=32;m>=1;m>>=1){ s += __shfl_xor(s,m,64); sq += __shfl_xor(sq,m,64); }
  __shared__ float rs[4], rq[4];
  int wv = threadIdx.x>>6;
  if ((threadIdx.x&63)==0){ rs[wv]=s; rq[wv]=sq; }
  __syncthreads();
  float S = rs[0]+rs[1]+rs[2]+rs[3];
  float Q = rq[0]+rq[1]+rq[2]+rq[3];
  float mean = S*(1.f/512.f);
  float var  = Q*(1.f/512.f) - mean*mean;
  float inv  = rsqrtf(var + 1e-5f);
  float o0 = (v0-mean)*inv*gg[c0] + bb[c0];
  float o1 = (v1-mean)*inv*gg[c1] + bb[c1];
  out[o+c0] = o0;
  out[o+c1] = o1;
  if (WBF) { outbf[o+c0] = __float2bfloat16(o0); outbf[o+c1] = __float2bfloat16(o1); }
}

extern "C" void kernel_launch(void* const* d_in, const int* in_sizes, int n_in,
                              void* d_out, int out_size, void* d_ws, size_t ws_size,
                              hipStream_t stream)
{
  const float* tgt    = (const float*)d_in[0];
  const float* W_in   = (const float*)d_in[1];
  const float* conv_w = (const float*)d_in[2];
  const float* conv_b = (const float*)d_in[3];
  const float* dt_bias= (const float*)d_in[4];
  const float* A_log  = (const float*)d_in[5];
  const float* D_skip = (const float*)d_in[6];
  const float* gnorm_w= (const float*)d_in[7];
  const float* W_out  = (const float*)d_in[8];
  const float* n1_g   = (const float*)d_in[9];
  const float* n1_b   = (const float*)d_in[10];
  const float* ffn_w1 = (const float*)d_in[11];
  const float* ffn_b1 = (const float*)d_in[12];
  const float* ffn_w2 = (const float*)d_in[13];
  const float* ffn_b2 = (const float*)d_in[14];
  const float* n3_g   = (const float*)d_in[15];
  const float* n3_b   = (const float*)d_in[16];
  float* out = (float*)d_out;
  float* ws  = (float*)d_ws;

  // ---- workspace layout (float offsets); weights get a DEDICATED region ----
  float* zx   = ws;                                   // 9,502,720
  float* xbcF = zx  + (size_t)NTOK*D_IN_PROJ;         // 2,621,440 (bf16 xbc)
  __hip_bfloat16* xbc = (__hip_bfloat16*)xbcF;
  float* dtp  = xbcF + 2621440;                       // 65,536
  float* yb   = dtp + 65536;                          // 4,194,304
  float* Sreg = yb  + 4194304;                        // 8,388,608 (Sbuf bf16)
  __hip_bfloat16* Sbuf = (__hip_bfloat16*)Sreg;
  float* lcend= Sreg + 8388608;                       // 2,048
  float* scl  = lcend + NCID;                         // 65,536
  float* wreg = scl + 65536;
  __hip_bfloat16* Wint  = (__hip_bfloat16*)wreg;                   // [2432][512]
  __hip_bfloat16* Woutt = (__hip_bfloat16*)(wreg + 622592);        // [512][1024]
  __hip_bfloat16* W1t   = (__hip_bfloat16*)(wreg + 622592+262144); // [2048][512]
  __hip_bfloat16* W2t   = (__hip_bfloat16*)(wreg + 622592+262144+524288); // [512][2048]
  __hip_bfloat16* tgt_bf= (__hip_bfloat16*)(wreg + 622592+262144+524288+524288);

  // aliases into dead regions
  __hip_bfloat16* yb_bf = (__hip_bfloat16*)xbcF;            // xbc dead after chunk_inter
  __hip_bfloat16* tb_bf = (__hip_bfloat16*)yb;              // yb dead after gate_rms
  float* tb   = Sreg;                                       // Sbuf dead after chunk_inter
  float* tmp0 = Sreg + 2097152;
  float* tmp1 = Sreg + 4194304;
  __hip_bfloat16* hmid_bf = (__hip_bfloat16*)zx;            // zx dead after gate_rms

  // 1) prep: all weight transposes + tgt->bf16 (ONE dispatch)
  prep_all<<<2048 + 76*16 + 16*32 + 64*16 + 16*64, 256, 0, stream>>>(
      tgt, tgt_bf, W_in, Wint, W_out, Woutt, ffn_w1, W1t, ffn_w2, W2t);
  // 2) in-proj (128x128)
  gemm128<0,float><<<dim3(NPJ_PAD/128, NTOK/128), 256, 0, stream>>>(
      tgt_bf, Wint, nullptr, zx, D_IN_PROJ, D_MODEL, D_IN_PROJ);
  // 3) conv + SiLU -> bf16 xbc (+ fused dt)
  conv_silu<<<dim3(CONV_DIM/256, SEQ/64, B_SZ), 256, 0, stream>>>(zx, conv_w, conv_b, xbc, dt_bias, dtp);
  // 4) chunked scan
  chunk_intra<<<NCID, 256, 0, stream>>>(xbc, dtp, A_log, D_skip, yb, Sbuf, lcend, scl);
  state_scan<<<B_SZ*NHEADS*4, 256, 0, stream>>>(Sbuf, lcend);
  chunk_inter<<<NCID, 256, 0, stream>>>(xbc, Sbuf, scl, yb);
  // 5) gate + RMSNorm -> bf16
  gate_rms<<<NTOK, 256, 0, stream>>>(zx, gnorm_w, yb, yb_bf);
  // 6) out-proj split-K=2: tmp0/tmp1
  gemm_bf16<0,float><<<dim3(D_MODEL/64, NTOK/128, 2), 256, 0, stream>>>(
      yb_bf, Woutt, nullptr, tmp0, D_MODEL, D_INNER, D_MODEL, NTOK, 2);
  // 7) tb = LayerNorm(tmp0 + tmp1 + tgt) (+ bf16 copy)
  add_ln<1><<<NTOK, 256, 0, stream>>>(tmp0, tmp1, tgt, n1_g, n1_b, tb, tb_bf);
  // 8) ffn1 (128x128, gelu) -> bf16 hmid
  gemm128<2,__hip_bfloat16><<<dim3(FF/128, NTOK/128), 256, 0, stream>>>(
      tb_bf, W1t, ffn_b1, hmid_bf, FF, D_MODEL, FF);
  // 9) ffn2 split-K=2 (+bias on z==0): tmp0/tmp1
  gemm_bf16<1,float><<<dim3(D_MODEL/64, NTOK/128, 2), 256, 0, stream>>>(
      hmid_bf, W2t, ffn_b2, tmp0, D_MODEL, FF, D_MODEL, NTOK, 2);
  // 10) out = LayerNorm(tmp0 + tmp1 + tb)
  add_ln<0><<<NTOK, 256, 0, stream>>>(tmp0, tmp1, tb, n3_g, n3_b, out, nullptr);
}